// Round 3
// baseline (1577.004 us; speedup 1.0000x reference)
//
#include <hip/hip_runtime.h>
#include <math.h>

constexpr int kN    = 100000;
constexpr int kE    = 3200000;
constexpr int kHid  = 1024;
constexpr int kZrow = 12;

// coarse buckets: 1024 nodes each
constexpr int kCBShift = 10;
constexpr int kCBNodes = 1 << kCBShift;                    // 1024
constexpr int kCB      = (kN + kCBNodes - 1) / kCBNodes;   // 98
constexpr int kCBCap   = 70000;                            // entries/bucket (mean 65536)
constexpr int kSplit   = 8;                                // sub-blocks per bucket
constexpr int kChunkE  = 2048;                             // edges per bucketize block
constexpr int kChunkEnt= kChunkE * 2;                      // 4096 staged entries

// ---------------------------------------------------------------------------
// Kernel 1: per-node MLP + derived columns.
// ---------------------------------------------------------------------------
__global__ __launch_bounds__(256) void mlp_kernel(
    const float* __restrict__ feat,
    const float* __restrict__ W1,
    const float* __restrict__ b1,
    const float* __restrict__ W2,
    const float* __restrict__ b2,
    float* __restrict__ z)
{
    int n = blockIdx.x * blockDim.x + threadIdx.x;
    if (n >= kN) return;

    const float4* fr = reinterpret_cast<const float4*>(feat + (size_t)n * 12);
    float4 f0 = fr[0], f1 = fr[1], f2 = fr[2];
    float f[12] = {f0.x, f0.y, f0.z, f0.w,
                   f1.x, f1.y, f1.z, f1.w,
                   f2.x, f2.y, f2.z, f2.w};

    float acc[8];
    #pragma unroll
    for (int o = 0; o < 8; ++o) acc[o] = b2[o];

    #pragma unroll 4
    for (int k = 0; k < kHid; ++k) {
        float h = b1[k];
        #pragma unroll
        for (int d = 0; d < 12; ++d) h = fmaf(f[d], W1[d * kHid + k], h);
        h = fmaxf(h, 0.0f);
        #pragma unroll
        for (int o = 0; o < 8; ++o) acc[o] = fmaf(h, W2[k * 8 + o], acc[o]);
    }

    float ymin_diff = (f[2] - f[10]) * 10.0f;
    bool mask = (f[0] <= f[5]) && (f[1] >= f[4]) &&
                (f[2] <= f[11]) && (f[3] >= f[10]);
    float inter = mask ? 5.0f : -5.0f;

    float* zr = z + (size_t)n * kZrow;
    reinterpret_cast<float4*>(zr)[0] = {acc[0], acc[1], acc[2], acc[3]};
    reinterpret_cast<float4*>(zr)[1] = {acc[4], acc[5], acc[6], acc[7]};
    reinterpret_cast<float4*>(zr)[2] = {ymin_diff, inter, 0.0f, 0.0f};
}

// ---------------------------------------------------------------------------
// Kernel 2: bucketize incidences into 98 coarse buckets, coalesced writes.
// Entry: .x = partner | (own_local<<17) ; .y = edge<<1 | side
// ---------------------------------------------------------------------------
__global__ __launch_bounds__(256) void bucketize(
    const int* __restrict__ sx,
    const int* __restrict__ sy,
    int* __restrict__ gcur,
    uint2* __restrict__ bdata)
{
    __shared__ int   cnt[128];
    __shared__ int   tmp[128];
    __shared__ int   startArr[129];
    __shared__ int   c2[128];
    __shared__ int   gbase[128];
    __shared__ uint2 stage[kChunkEnt];

    int tid  = threadIdx.x;
    int e0   = blockIdx.x * kChunkE;
    int ecnt = min(kChunkE, kE - e0);

    if (tid < 128) cnt[tid] = 0;
    __syncthreads();

    // Phase A: count (and stash endpoints in registers)
    int ea[kChunkE / 256], eb[kChunkE / 256];
    int ne = 0;
    for (int i = tid; i < ecnt; i += 256) {
        int a = sx[e0 + i];
        int b = sy[e0 + i];
        ea[ne] = a; eb[ne] = b; ++ne;
        atomicAdd(&cnt[a >> kCBShift], 1);
        atomicAdd(&cnt[b >> kCBShift], 1);
    }
    __syncthreads();

    // Phase B: exclusive scan of cnt[0..127]
    if (tid < 128) tmp[tid] = cnt[tid];
    __syncthreads();
    for (int off = 1; off < 128; off <<= 1) {
        int v = 0;
        if (tid < 128 && tid >= off) v = tmp[tid - off];
        __syncthreads();
        if (tid < 128) tmp[tid] += v;
        __syncthreads();
    }
    if (tid < 128) startArr[tid] = tmp[tid] - cnt[tid];
    if (tid == 127) startArr[128] = tmp[127];
    __syncthreads();

    // Phase B2: reserve global ranges (one atomic per bucket per block)
    if (tid < 128) {
        int c = (tid < kCB) ? cnt[tid] : 0;
        gbase[tid] = (c > 0) ? atomicAdd(&gcur[tid], c) : 0;
        c2[tid] = startArr[tid];
    }
    __syncthreads();

    // Phase C1: stage entries grouped by bucket
    ne = 0;
    for (int i = tid; i < ecnt; i += 256) {
        int a = ea[ne], b = eb[ne]; ++ne;
        unsigned e2 = (unsigned)((e0 + i) << 1);
        int sa = atomicAdd(&c2[a >> kCBShift], 1);
        stage[sa] = make_uint2((unsigned)b | ((unsigned)(a & (kCBNodes - 1)) << 17), e2);
        int sb = atomicAdd(&c2[b >> kCBShift], 1);
        stage[sb] = make_uint2((unsigned)a | ((unsigned)(b & (kCBNodes - 1)) << 17), e2 | 1u);
    }
    __syncthreads();

    // Phase C2: flush runs coalesced; bucket found by binary search in startArr
    int total = 2 * ecnt;
    for (int j = tid; j < total; j += 256) {
        int lo = 0, hi = kCB;
        while (hi - lo > 1) {
            int mid = (lo + hi) >> 1;
            if (startArr[mid] <= j) lo = mid; else hi = mid;
        }
        int idx = gbase[lo] + (j - startArr[lo]);
        if (idx < kCBCap)
            bdata[(size_t)lo * kCBCap + idx] = stage[j];
    }
}

// ---------------------------------------------------------------------------
// Kernel 3: per-layer gather, LDS-atomic accumulation, partial outputs.
// ---------------------------------------------------------------------------
__global__ __launch_bounds__(256) void kenn_gather_part(
    const float* __restrict__ zin,
    const float* __restrict__ rel,
    const int* __restrict__ gcur,
    const uint2* __restrict__ bdata,
    const float* __restrict__ cw,
    int layer,
    float* __restrict__ partials)
{
    __shared__ float delta[kCBNodes * 10];   // 40 KB

    int tid = threadIdx.x;
    int b   = blockIdx.x / kSplit;
    int sub = blockIdx.x % kSplit;

    for (int i = tid; i < kCBNodes * 10; i += 256) delta[i] = 0.0f;
    __syncthreads();

    float w  = cw[layer];
    float sw = fmaxf(w, 0.0f) + log1pf(__expf(-fabsf(w)));  // softplus

    int cnt = min(gcur[b], kCBCap);
    int j0  = (int)((long long)cnt * sub / kSplit);
    int j1  = (int)((long long)cnt * (sub + 1) / kSplit);
    const uint2* bd = bdata + (size_t)b * kCBCap;

    for (int j = j0 + tid; j < j1; j += 256) {
        uint2 ent = bd[j];
        int partner = (int)(ent.x & 0x1FFFFu);
        int ol      = (int)((ent.x >> 17) & 0x3FFu);
        int side    = (int)(ent.y & 1u);
        int e       = (int)(ent.y >> 1);
        int own     = (b << kCBShift) + ol;

        float2 r = reinterpret_cast<const float2*>(rel)[e];
        const float* zo = zin + (size_t)own * kZrow;
        const float* zp = zin + (size_t)partner * kZrow;
        float4 o0 = reinterpret_cast<const float4*>(zo)[0];
        float4 o1 = reinterpret_cast<const float4*>(zo)[1];
        float2 o2 = reinterpret_cast<const float2*>(zo + 8)[0];
        float4 p0 = reinterpret_cast<const float4*>(zp)[0];
        float4 p1 = reinterpret_cast<const float4*>(zp)[1];
        float2 p2 = reinterpret_cast<const float2*>(zp + 8)[0];

        float self[10] = {o0.x, o0.y, o0.z, o0.w, o1.x, o1.y, o1.z, o1.w, o2.x, o2.y};
        float part[10] = {p0.x, p0.y, p0.z, p0.w, p1.x, p1.y, p1.z, p1.w, p2.x, p2.y};

        float t[22];
        #pragma unroll
        for (int jj = 0; jj < 10; ++jj) {
            float ga = side ? part[jj] : self[jj];   // z[sx] value
            float gb = side ? self[jj] : part[jj];   // z[sy] value
            t[jj]      = (jj & 1) ? -ga : ga;
            t[10 + jj] = (jj & 1) ? -gb : gb;
        }
        t[20] = r.x;
        t[21] = -r.y;

        float m = t[0];
        #pragma unroll
        for (int jj = 1; jj < 22; ++jj) m = fmaxf(m, t[jj]);

        float pe[22];
        float ssum = 0.0f;
        #pragma unroll
        for (int jj = 0; jj < 22; ++jj) { pe[jj] = __expf(t[jj] - m); ssum += pe[jj]; }

        float scale = sw / ssum;
        #pragma unroll
        for (int jj = 0; jj < 10; ++jj) {
            float pv = side ? pe[10 + jj] : pe[jj];
            atomicAdd(&delta[ol * 10 + jj], ((jj & 1) ? -scale : scale) * pv);
        }
    }
    __syncthreads();

    float* dst = partials + (size_t)blockIdx.x * (kCBNodes * 10);
    for (int i = tid; i < kCBNodes * 10; i += 256) dst[i] = delta[i];
}

// ---------------------------------------------------------------------------
// Kernel 4: reduce kSplit partials + zin -> zout
// ---------------------------------------------------------------------------
__global__ __launch_bounds__(256) void kenn_reduce(
    const float* __restrict__ zin,
    float* __restrict__ zout,
    const float* __restrict__ partials)
{
    int n = blockIdx.x * blockDim.x + threadIdx.x;
    if (n >= kN) return;
    int b  = n >> kCBShift;
    int ol = n & (kCBNodes - 1);

    float acc[10] = {0,0,0,0,0,0,0,0,0,0};
    const float* base = partials + ((size_t)b * kSplit) * (kCBNodes * 10) + ol * 10;
    #pragma unroll
    for (int s = 0; s < kSplit; ++s) {
        const float* p = base + (size_t)s * (kCBNodes * 10);
        #pragma unroll
        for (int j = 0; j < 10; ++j) acc[j] += p[j];
    }

    const float* zi = zin + (size_t)n * kZrow;
    float4 z0 = reinterpret_cast<const float4*>(zi)[0];
    float4 z1 = reinterpret_cast<const float4*>(zi)[1];
    float4 z2 = reinterpret_cast<const float4*>(zi)[2];

    float* zo = zout + (size_t)n * kZrow;
    reinterpret_cast<float4*>(zo)[0] = {z0.x + acc[0], z0.y + acc[1], z0.z + acc[2], z0.w + acc[3]};
    reinterpret_cast<float4*>(zo)[1] = {z1.x + acc[4], z1.y + acc[5], z1.z + acc[6], z1.w + acc[7]};
    reinterpret_cast<float4*>(zo)[2] = {z2.x + acc[8], z2.y + acc[9], z2.z, z2.w};
}

// ---------------------------------------------------------------------------
// Kernel 5: output heads.
// ---------------------------------------------------------------------------
__global__ __launch_bounds__(256) void out_kernel(
    const float* __restrict__ z,
    float* __restrict__ out)
{
    int n = blockIdx.x * blockDim.x + threadIdx.x;
    if (n >= kN) return;

    const float* zr = z + (size_t)n * kZrow;
    float4 za = reinterpret_cast<const float4*>(zr)[0];
    float4 zb = reinterpret_cast<const float4*>(zr)[1];

    float ma = fmaxf(fmaxf(za.x, za.y), fmaxf(za.z, za.w));
    float ea0 = __expf(za.x - ma), ea1 = __expf(za.y - ma);
    float ea2 = __expf(za.z - ma), ea3 = __expf(za.w - ma);
    float ia = 1.0f / (ea0 + ea1 + ea2 + ea3);
    float4 sma = {ea0 * ia, ea1 * ia, ea2 * ia, ea3 * ia};

    float mb = fmaxf(fmaxf(zb.x, zb.y), fmaxf(zb.z, zb.w));
    float eb0 = __expf(zb.x - mb), eb1 = __expf(zb.y - mb);
    float eb2 = __expf(zb.z - mb), eb3 = __expf(zb.w - mb);
    float ib = 1.0f / (eb0 + eb1 + eb2 + eb3);
    float4 smb = {eb0 * ib, eb1 * ib, eb2 * ib, eb3 * ib};

    reinterpret_cast<float4*>(out)[n]           = za;
    reinterpret_cast<float4*>(out + 4 * kN)[n]  = sma;
    reinterpret_cast<float4*>(out + 8 * kN)[n]  = zb;
    reinterpret_cast<float4*>(out + 12 * kN)[n] = smb;
}

// ---------------------------------------------------------------------------
// Fallback (R1 path), used only if ws too small.
// ---------------------------------------------------------------------------
__global__ __launch_bounds__(256) void edge_kernel(
    const float* __restrict__ zin,
    float* __restrict__ zout,
    const float* __restrict__ rel,
    const int* __restrict__ sx,
    const int* __restrict__ sy,
    const float* __restrict__ cw,
    int layer)
{
    int e = blockIdx.x * blockDim.x + threadIdx.x;
    if (e >= kE) return;

    float w  = cw[layer];
    float sw = fmaxf(w, 0.0f) + log1pf(__expf(-fabsf(w)));

    int a = sx[e];
    int b = sy[e];
    float2 r = reinterpret_cast<const float2*>(rel)[e];

    const float* za = zin + (size_t)a * kZrow;
    const float* zb = zin + (size_t)b * kZrow;
    float4 a0 = reinterpret_cast<const float4*>(za)[0];
    float4 a1 = reinterpret_cast<const float4*>(za)[1];
    float2 a2 = reinterpret_cast<const float2*>(za + 8)[0];
    float4 b0 = reinterpret_cast<const float4*>(zb)[0];
    float4 b1v = reinterpret_cast<const float4*>(zb)[1];
    float2 b2v = reinterpret_cast<const float2*>(zb + 8)[0];

    float t[22];
    t[0]  =  a0.x;  t[1]  = -a0.y;  t[2]  =  a0.z;  t[3]  = -a0.w;
    t[4]  =  a1.x;  t[5]  = -a1.y;  t[6]  =  a1.z;  t[7]  = -a1.w;
    t[8]  =  a2.x;  t[9]  = -a2.y;
    t[10] =  b0.x;  t[11] = -b0.y;  t[12] =  b0.z;  t[13] = -b0.w;
    t[14] =  b1v.x; t[15] = -b1v.y; t[16] =  b1v.z; t[17] = -b1v.w;
    t[18] =  b2v.x; t[19] = -b2v.y;
    t[20] =  r.x;   t[21] = -r.y;

    float m = t[0];
    #pragma unroll
    for (int i = 1; i < 22; ++i) m = fmaxf(m, t[i]);
    float p[22]; float s = 0.0f;
    #pragma unroll
    for (int i = 0; i < 22; ++i) { p[i] = __expf(t[i] - m); s += p[i]; }
    float scale = sw / s;

    float* oa = zout + (size_t)a * kZrow;
    float* ob = zout + (size_t)b * kZrow;
    #pragma unroll
    for (int i = 0; i < 10; ++i)
        unsafeAtomicAdd(oa + i, ((i & 1) ? -scale : scale) * p[i]);
    #pragma unroll
    for (int i = 0; i < 10; ++i)
        unsafeAtomicAdd(ob + i, ((i & 1) ? -scale : scale) * p[10 + i]);
}

// ---------------------------------------------------------------------------
extern "C" void kernel_launch(void* const* d_in, const int* in_sizes, int n_in,
                              void* d_out, int out_size, void* d_ws, size_t ws_size,
                              hipStream_t stream)
{
    const float* feat = (const float*)d_in[0];
    const float* rel  = (const float*)d_in[1];
    const float* W1   = (const float*)d_in[2];
    const float* b1   = (const float*)d_in[3];
    const float* W2   = (const float*)d_in[4];
    const float* b2   = (const float*)d_in[5];
    const float* cw   = (const float*)d_in[6];
    const int*   sx   = (const int*)d_in[7];
    const int*   sy   = (const int*)d_in[8];
    float* out = (float*)d_out;

    // ws layout (bytes):
    // zA 0..4.8M | zB 4.8M..9.6M | gcur 9.6M (512B) | bdata | partials
    char* ws = (char*)d_ws;
    float* zA   = (float*)ws;
    float* zB   = (float*)(ws + 4800000);
    int*   gcur = (int*)  (ws + 9600000);
    uint2* bdata= (uint2*)(ws + 9601024);
    size_t bdataBytes = (size_t)kCB * kCBCap * sizeof(uint2);     // 54.88 MB
    float* partials = (float*)(ws + 9601024 + bdataBytes);
    size_t partBytes = (size_t)kCB * kSplit * kCBNodes * 10 * 4;  // 32.1 MB
    size_t need = 9601024 + bdataBytes + partBytes;

    dim3 blk(256);
    dim3 gN((kN + 255) / 256);
    dim3 gE((kE + 255) / 256);

    mlp_kernel<<<gN, blk, 0, stream>>>(feat, W1, b1, W2, b2, zA);

    if (ws_size >= need) {
        hipMemsetAsync(gcur, 0, 512, stream);
        bucketize<<<dim3((kE + kChunkE - 1) / kChunkE), blk, 0, stream>>>(sx, sy, gcur, bdata);

        dim3 gG(kCB * kSplit);
        kenn_gather_part<<<gG, blk, 0, stream>>>(zA, rel, gcur, bdata, cw, 0, partials);
        kenn_reduce<<<gN, blk, 0, stream>>>(zA, zB, partials);
        kenn_gather_part<<<gG, blk, 0, stream>>>(zB, rel, gcur, bdata, cw, 1, partials);
        kenn_reduce<<<gN, blk, 0, stream>>>(zB, zA, partials);
        kenn_gather_part<<<gG, blk, 0, stream>>>(zA, rel, gcur, bdata, cw, 2, partials);
        kenn_reduce<<<gN, blk, 0, stream>>>(zA, zB, partials);

        out_kernel<<<gN, blk, 0, stream>>>(zB, out);
    } else {
        size_t zbytes = (size_t)kN * kZrow * sizeof(float);
        hipMemcpyAsync(zB, zA, zbytes, hipMemcpyDeviceToDevice, stream);
        edge_kernel<<<gE, blk, 0, stream>>>(zA, zB, rel, sx, sy, cw, 0);
        hipMemcpyAsync(zA, zB, zbytes, hipMemcpyDeviceToDevice, stream);
        edge_kernel<<<gE, blk, 0, stream>>>(zB, zA, rel, sx, sy, cw, 1);
        hipMemcpyAsync(zB, zA, zbytes, hipMemcpyDeviceToDevice, stream);
        edge_kernel<<<gE, blk, 0, stream>>>(zA, zB, rel, sx, sy, cw, 2);
        out_kernel<<<gN, blk, 0, stream>>>(zB, out);
    }
}

// Round 6
// 758.621 us; speedup vs baseline: 2.0788x; 2.0788x over previous
//
#include <hip/hip_runtime.h>
#include <math.h>

constexpr int kN    = 100000;
constexpr int kE    = 3200000;
constexpr int kHid  = 1024;
constexpr int kZrow = 12;

// coarse buckets: 1024 nodes each
constexpr int kCBShift = 10;
constexpr int kCBNodes = 1 << kCBShift;                    // 1024
constexpr int kCB      = (kN + kCBNodes - 1) / kCBNodes;   // 98
constexpr int kCBCap   = 70000;                            // entries/bucket (mean 65306, 17 sigma headroom)
constexpr int kChunkE  = 1024;                             // edges per bucketize block
constexpr int kChunkEnt= kChunkE * 2;                      // 2048 staged entries
constexpr int kSplit   = 10;                               // sub-blocks/bucket (fallback path)

// key layout: partner[16:0] | own_local[26:17] | side[27]

// ---------------------------------------------------------------------------
// Kernel 1: per-node MLP + derived columns.
// ---------------------------------------------------------------------------
__global__ __launch_bounds__(256) void mlp_kernel(
    const float* __restrict__ feat,
    const float* __restrict__ W1,
    const float* __restrict__ b1,
    const float* __restrict__ W2,
    const float* __restrict__ b2,
    float* __restrict__ z)
{
    int n = blockIdx.x * blockDim.x + threadIdx.x;
    if (n >= kN) return;

    const float4* fr = reinterpret_cast<const float4*>(feat + (size_t)n * 12);
    float4 f0 = fr[0], f1 = fr[1], f2 = fr[2];
    float f[12] = {f0.x, f0.y, f0.z, f0.w,
                   f1.x, f1.y, f1.z, f1.w,
                   f2.x, f2.y, f2.z, f2.w};

    float acc[8];
    #pragma unroll
    for (int o = 0; o < 8; ++o) acc[o] = b2[o];

    #pragma unroll 4
    for (int k = 0; k < kHid; ++k) {
        float h = b1[k];
        #pragma unroll
        for (int d = 0; d < 12; ++d) h = fmaf(f[d], W1[d * kHid + k], h);
        h = fmaxf(h, 0.0f);
        #pragma unroll
        for (int o = 0; o < 8; ++o) acc[o] = fmaf(h, W2[k * 8 + o], acc[o]);
    }

    float ymin_diff = (f[2] - f[10]) * 10.0f;
    bool mask = (f[0] <= f[5]) && (f[1] >= f[4]) &&
                (f[2] <= f[11]) && (f[3] >= f[10]);
    float inter = mask ? 5.0f : -5.0f;

    float* zr = z + (size_t)n * kZrow;
    reinterpret_cast<float4*>(zr)[0] = {acc[0], acc[1], acc[2], acc[3]};
    reinterpret_cast<float4*>(zr)[1] = {acc[4], acc[5], acc[6], acc[7]};
    reinterpret_cast<float4*>(zr)[2] = {ymin_diff, inter, 0.0f, 0.0f};
}

// ---------------------------------------------------------------------------
// Kernel 2: bucketize incidences into 98 coarse buckets (SoA, rel embedded).
// Coalesced run-writes into exclusively reserved ranges.
// ---------------------------------------------------------------------------
__global__ __launch_bounds__(256) void bucketize(
    const int* __restrict__ sx,
    const int* __restrict__ sy,
    const float* __restrict__ rel,
    int* __restrict__ gcur,
    unsigned* __restrict__ bkey,
    float2* __restrict__ brel)
{
    __shared__ int      cnt[128];
    __shared__ int      scn[128];
    __shared__ int      startArr[129];
    __shared__ int      c2[128];
    __shared__ int      gbase[128];
    __shared__ unsigned stage_k[kChunkEnt];
    __shared__ float2   stage_r[kChunkEnt];

    int tid  = threadIdx.x;
    int e0   = blockIdx.x * kChunkE;
    int ecnt = min(kChunkE, kE - e0);

    if (tid < 128) cnt[tid] = 0;
    __syncthreads();

    int ea[kChunkE / 256], eb[kChunkE / 256];
    int ne = 0;
    for (int i = tid; i < ecnt; i += 256) {
        int a = sx[e0 + i];
        int b = sy[e0 + i];
        ea[ne] = a; eb[ne] = b; ++ne;
        atomicAdd(&cnt[a >> kCBShift], 1);
        atomicAdd(&cnt[b >> kCBShift], 1);
    }
    __syncthreads();

    if (tid < 128) scn[tid] = cnt[tid];
    __syncthreads();
    for (int off = 1; off < 128; off <<= 1) {
        int v = 0;
        if (tid < 128 && tid >= off) v = scn[tid - off];
        __syncthreads();
        if (tid < 128) scn[tid] += v;
        __syncthreads();
    }
    if (tid < 128) startArr[tid] = scn[tid] - cnt[tid];
    if (tid == 127) startArr[128] = scn[127];
    __syncthreads();

    if (tid < 128) {
        int c = (tid < kCB) ? cnt[tid] : 0;
        gbase[tid] = (c > 0) ? atomicAdd(&gcur[tid], c) : 0;
        c2[tid] = startArr[tid];
    }
    __syncthreads();

    ne = 0;
    for (int i = tid; i < ecnt; i += 256) {
        int a = ea[ne], b = eb[ne]; ++ne;
        float2 r = reinterpret_cast<const float2*>(rel)[e0 + i];
        int sa = atomicAdd(&c2[a >> kCBShift], 1);
        stage_k[sa] = (unsigned)b | ((unsigned)(a & (kCBNodes - 1)) << 17);
        stage_r[sa] = r;
        int sb = atomicAdd(&c2[b >> kCBShift], 1);
        stage_k[sb] = (unsigned)a | ((unsigned)(b & (kCBNodes - 1)) << 17) | (1u << 27);
        stage_r[sb] = r;
    }
    __syncthreads();

    int total = 2 * ecnt;
    for (int j = tid; j < total; j += 256) {
        int lo = 0, hi = kCB;
        while (hi - lo > 1) {
            int mid = (lo + hi) >> 1;
            if (startArr[mid] <= j) lo = mid; else hi = mid;
        }
        int idx = gbase[lo] + (j - startArr[lo]);
        if (idx < kCBCap) {
            size_t dst = (size_t)lo * kCBCap + idx;
            bkey[dst] = stage_k[j];
            brel[dst] = stage_r[j];
        }
    }
}

// ---------------------------------------------------------------------------
// Kernel 3 (CSR path): counting-sort one bucket by own_local -> CSR.
// Scattered writes confined to a ~0.8 MB L2-resident window.
// ---------------------------------------------------------------------------
__global__ __launch_bounds__(1024) void sort_bucket(
    const int* __restrict__ gcur,
    const unsigned* __restrict__ bkey,
    const float2* __restrict__ brel,
    unsigned* __restrict__ skey,
    float2* __restrict__ srel,
    int* __restrict__ rowptr,
    int* __restrict__ rowcnt)
{
    __shared__ int cnt1024[kCBNodes];
    __shared__ int scanb[kCBNodes];
    __shared__ int cur[kCBNodes];

    int tid = threadIdx.x;
    int b   = blockIdx.x;
    int n   = min(gcur[b], kCBCap);
    const unsigned* bk = bkey + (size_t)b * kCBCap;
    const float2*   br = brel + (size_t)b * kCBCap;

    cnt1024[tid] = 0;
    __syncthreads();

    for (int j = tid; j < n; j += 1024)
        atomicAdd(&cnt1024[(bk[j] >> 17) & 1023u], 1);
    __syncthreads();

    scanb[tid] = cnt1024[tid];
    __syncthreads();
    for (int off = 1; off < kCBNodes; off <<= 1) {
        int v = (tid >= off) ? scanb[tid - off] : 0;
        __syncthreads();
        scanb[tid] += v;
        __syncthreads();
    }
    int excl = scanb[tid] - cnt1024[tid];
    cur[tid] = excl;

    int node = (b << kCBShift) + tid;
    if (node < kN) {
        rowptr[node] = b * kCBCap + excl;
        rowcnt[node] = cnt1024[tid];
    }
    __syncthreads();

    for (int j = tid; j < n; j += 1024) {
        unsigned k = bk[j];
        float2  r  = br[j];
        int ol = (int)((k >> 17) & 1023u);
        int pos = atomicAdd(&cur[ol], 1);
        size_t dst = (size_t)b * kCBCap + pos;
        skey[dst] = k;
        srel[dst] = r;
    }
}

// ---------------------------------------------------------------------------
// Kernel 4 (CSR path): gather layer, register accumulation, no atomics.
// ---------------------------------------------------------------------------
__global__ __launch_bounds__(256) void kenn_gather_csr(
    const float* __restrict__ zin,
    float* __restrict__ zout,
    const unsigned* __restrict__ skey,
    const float2* __restrict__ srel,
    const int* __restrict__ rowptr,
    const int* __restrict__ rowcnt,
    const float* __restrict__ cw,
    int layer)
{
    int node = blockIdx.x * 16 + (threadIdx.x >> 4);
    int lane = threadIdx.x & 15;
    if (node >= kN) return;

    float w  = cw[layer];
    float sw = fmaxf(w, 0.0f) + log1pf(__expf(-fabsf(w)));  // softplus

    const float* zs = zin + (size_t)node * kZrow;
    float4 s0 = reinterpret_cast<const float4*>(zs)[0];
    float4 s1 = reinterpret_cast<const float4*>(zs)[1];
    float4 s2 = reinterpret_cast<const float4*>(zs)[2];
    float self[10] = {s0.x, s0.y, s0.z, s0.w, s1.x, s1.y, s1.z, s1.w, s2.x, s2.y};

    float acc[10] = {0,0,0,0,0,0,0,0,0,0};
    int rp = rowptr[node];
    int rc = rowcnt[node];

    for (int i = lane; i < rc; i += 16) {
        unsigned k = skey[rp + i];
        float2  r  = srel[rp + i];
        int p    = (int)(k & 0x1FFFFu);
        int side = (int)((k >> 27) & 1u);

        const float* zp = zin + (size_t)p * kZrow;
        float4 p0 = reinterpret_cast<const float4*>(zp)[0];
        float4 p1 = reinterpret_cast<const float4*>(zp)[1];
        float2 p2 = reinterpret_cast<const float2*>(zp + 8)[0];
        float part[10] = {p0.x, p0.y, p0.z, p0.w, p1.x, p1.y, p1.z, p1.w, p2.x, p2.y};

        float t[22];
        #pragma unroll
        for (int j = 0; j < 10; ++j) {
            float ga = side ? part[j] : self[j];   // z[sx] value
            float gb = side ? self[j] : part[j];   // z[sy] value
            t[j]      = (j & 1) ? -ga : ga;
            t[10 + j] = (j & 1) ? -gb : gb;
        }
        t[20] = r.x;
        t[21] = -r.y;

        float m = t[0];
        #pragma unroll
        for (int j = 1; j < 22; ++j) m = fmaxf(m, t[j]);

        float pe[22];
        float ssum = 0.0f;
        #pragma unroll
        for (int j = 0; j < 22; ++j) { pe[j] = __expf(t[j] - m); ssum += pe[j]; }

        float scale = sw / ssum;
        #pragma unroll
        for (int j = 0; j < 10; ++j) {
            float pv = side ? pe[10 + j] : pe[j];
            acc[j] += ((j & 1) ? -scale : scale) * pv;
        }
    }

    #pragma unroll
    for (int m16 = 8; m16 >= 1; m16 >>= 1) {
        #pragma unroll
        for (int j = 0; j < 10; ++j)
            acc[j] += __shfl_xor(acc[j], m16, 16);
    }

    if (lane == 0) {
        float* zo = zout + (size_t)node * kZrow;
        reinterpret_cast<float4*>(zo)[0] =
            {self[0] + acc[0], self[1] + acc[1], self[2] + acc[2], self[3] + acc[3]};
        reinterpret_cast<float4*>(zo)[1] =
            {self[4] + acc[4], self[5] + acc[5], self[6] + acc[6], self[7] + acc[7]};
        reinterpret_cast<float4*>(zo)[2] =
            {self[8] + acc[8], self[9] + acc[9], s2.z, s2.w};
    }
}

// ---------------------------------------------------------------------------
// Fallback path A (R3-fixed): LDS-accum gather on unsorted buckets + reduce.
// ---------------------------------------------------------------------------
__global__ __launch_bounds__(256) void kenn_gather_part(
    const float* __restrict__ zin,
    const int* __restrict__ gcur,
    const unsigned* __restrict__ bkey,
    const float2* __restrict__ brel,
    const float* __restrict__ cw,
    int layer,
    float* __restrict__ partials)
{
    __shared__ float delta[kCBNodes * 10];   // 40 KB

    int tid = threadIdx.x;
    int b   = blockIdx.x / kSplit;
    int sub = blockIdx.x % kSplit;

    for (int i = tid; i < kCBNodes * 10; i += 256) delta[i] = 0.0f;
    __syncthreads();

    float w  = cw[layer];
    float sw = fmaxf(w, 0.0f) + log1pf(__expf(-fabsf(w)));

    int cnt = min(gcur[b], kCBCap);
    int j0  = (int)((long long)cnt * sub / kSplit);
    int j1  = (int)((long long)cnt * (sub + 1) / kSplit);
    const unsigned* bk = bkey + (size_t)b * kCBCap;
    const float2*   br = brel + (size_t)b * kCBCap;

    for (int j = j0 + tid; j < j1; j += 256) {
        unsigned k = bk[j];
        float2  r  = br[j];
        int partner = (int)(k & 0x1FFFFu);
        int ol      = (int)((k >> 17) & 1023u);
        int side    = (int)((k >> 27) & 1u);
        int own     = (b << kCBShift) + ol;

        const float* zo = zin + (size_t)own * kZrow;
        const float* zp = zin + (size_t)partner * kZrow;
        float4 o0 = reinterpret_cast<const float4*>(zo)[0];
        float4 o1 = reinterpret_cast<const float4*>(zo)[1];
        float2 o2 = reinterpret_cast<const float2*>(zo + 8)[0];
        float4 p0 = reinterpret_cast<const float4*>(zp)[0];
        float4 p1 = reinterpret_cast<const float4*>(zp)[1];
        float2 p2 = reinterpret_cast<const float2*>(zp + 8)[0];

        float self[10] = {o0.x, o0.y, o0.z, o0.w, o1.x, o1.y, o1.z, o1.w, o2.x, o2.y};
        float part[10] = {p0.x, p0.y, p0.z, p0.w, p1.x, p1.y, p1.z, p1.w, p2.x, p2.y};

        float t[22];
        #pragma unroll
        for (int jj = 0; jj < 10; ++jj) {
            float ga = side ? part[jj] : self[jj];
            float gb = side ? self[jj] : part[jj];
            t[jj]      = (jj & 1) ? -ga : ga;
            t[10 + jj] = (jj & 1) ? -gb : gb;
        }
        t[20] = r.x;
        t[21] = -r.y;

        float m = t[0];
        #pragma unroll
        for (int jj = 1; jj < 22; ++jj) m = fmaxf(m, t[jj]);

        float pe[22];
        float ssum = 0.0f;
        #pragma unroll
        for (int jj = 0; jj < 22; ++jj) { pe[jj] = __expf(t[jj] - m); ssum += pe[jj]; }

        float scale = sw / ssum;
        #pragma unroll
        for (int jj = 0; jj < 10; ++jj) {
            float pv = side ? pe[10 + jj] : pe[jj];
            atomicAdd(&delta[ol * 10 + jj], ((jj & 1) ? -scale : scale) * pv);
        }
    }
    __syncthreads();

    float* dst = partials + (size_t)blockIdx.x * (kCBNodes * 10);
    for (int i = tid; i < kCBNodes * 10; i += 256) dst[i] = delta[i];
}

__global__ __launch_bounds__(256) void kenn_reduce(
    const float* __restrict__ zin,
    float* __restrict__ zout,
    const float* __restrict__ partials)
{
    int n = blockIdx.x * blockDim.x + threadIdx.x;
    if (n >= kN) return;
    int b  = n >> kCBShift;
    int ol = n & (kCBNodes - 1);

    float acc[10] = {0,0,0,0,0,0,0,0,0,0};
    const float* base = partials + ((size_t)b * kSplit) * (kCBNodes * 10) + ol * 10;
    #pragma unroll
    for (int s = 0; s < kSplit; ++s) {
        const float* p = base + (size_t)s * (kCBNodes * 10);
        #pragma unroll
        for (int j = 0; j < 10; ++j) acc[j] += p[j];
    }

    const float* zi = zin + (size_t)n * kZrow;
    float4 z0 = reinterpret_cast<const float4*>(zi)[0];
    float4 z1 = reinterpret_cast<const float4*>(zi)[1];
    float4 z2 = reinterpret_cast<const float4*>(zi)[2];

    float* zo = zout + (size_t)n * kZrow;
    reinterpret_cast<float4*>(zo)[0] = {z0.x + acc[0], z0.y + acc[1], z0.z + acc[2], z0.w + acc[3]};
    reinterpret_cast<float4*>(zo)[1] = {z1.x + acc[4], z1.y + acc[5], z1.z + acc[6], z1.w + acc[7]};
    reinterpret_cast<float4*>(zo)[2] = {z2.x + acc[8], z2.y + acc[9], z2.z, z2.w};
}

// ---------------------------------------------------------------------------
// Kernel 5: output heads.
// ---------------------------------------------------------------------------
__global__ __launch_bounds__(256) void out_kernel(
    const float* __restrict__ z,
    float* __restrict__ out)
{
    int n = blockIdx.x * blockDim.x + threadIdx.x;
    if (n >= kN) return;

    const float* zr = z + (size_t)n * kZrow;
    float4 za = reinterpret_cast<const float4*>(zr)[0];
    float4 zb = reinterpret_cast<const float4*>(zr)[1];

    float ma = fmaxf(fmaxf(za.x, za.y), fmaxf(za.z, za.w));
    float ea0 = __expf(za.x - ma), ea1 = __expf(za.y - ma);
    float ea2 = __expf(za.z - ma), ea3 = __expf(za.w - ma);
    float ia = 1.0f / (ea0 + ea1 + ea2 + ea3);
    float4 sma = {ea0 * ia, ea1 * ia, ea2 * ia, ea3 * ia};

    float mb = fmaxf(fmaxf(zb.x, zb.y), fmaxf(zb.z, zb.w));
    float eb0 = __expf(zb.x - mb), eb1 = __expf(zb.y - mb);
    float eb2 = __expf(zb.z - mb), eb3 = __expf(zb.w - mb);
    float ib = 1.0f / (eb0 + eb1 + eb2 + eb3);
    float4 smb = {eb0 * ib, eb1 * ib, eb2 * ib, eb3 * ib};

    reinterpret_cast<float4*>(out)[n]           = za;
    reinterpret_cast<float4*>(out + 4 * kN)[n]  = sma;
    reinterpret_cast<float4*>(out + 8 * kN)[n]  = zb;
    reinterpret_cast<float4*>(out + 12 * kN)[n] = smb;
}

// ---------------------------------------------------------------------------
// Fallback path B (R1): atomic scatter, minimal ws.
// ---------------------------------------------------------------------------
__global__ __launch_bounds__(256) void edge_kernel(
    const float* __restrict__ zin,
    float* __restrict__ zout,
    const float* __restrict__ rel,
    const int* __restrict__ sx,
    const int* __restrict__ sy,
    const float* __restrict__ cw,
    int layer)
{
    int e = blockIdx.x * blockDim.x + threadIdx.x;
    if (e >= kE) return;

    float w  = cw[layer];
    float sw = fmaxf(w, 0.0f) + log1pf(__expf(-fabsf(w)));

    int a = sx[e];
    int b = sy[e];
    float2 r = reinterpret_cast<const float2*>(rel)[e];

    const float* za = zin + (size_t)a * kZrow;
    const float* zb = zin + (size_t)b * kZrow;
    float4 a0 = reinterpret_cast<const float4*>(za)[0];
    float4 a1 = reinterpret_cast<const float4*>(za)[1];
    float2 a2 = reinterpret_cast<const float2*>(za + 8)[0];
    float4 b0 = reinterpret_cast<const float4*>(zb)[0];
    float4 b1v = reinterpret_cast<const float4*>(zb)[1];
    float2 b2v = reinterpret_cast<const float2*>(zb + 8)[0];

    float t[22];
    t[0]  =  a0.x;  t[1]  = -a0.y;  t[2]  =  a0.z;  t[3]  = -a0.w;
    t[4]  =  a1.x;  t[5]  = -a1.y;  t[6]  =  a1.z;  t[7]  = -a1.w;
    t[8]  =  a2.x;  t[9]  = -a2.y;
    t[10] =  b0.x;  t[11] = -b0.y;  t[12] =  b0.z;  t[13] = -b0.w;
    t[14] =  b1v.x; t[15] = -b1v.y; t[16] =  b1v.z; t[17] = -b1v.w;
    t[18] =  b2v.x; t[19] = -b2v.y;
    t[20] =  r.x;   t[21] = -r.y;

    float m = t[0];
    #pragma unroll
    for (int i = 1; i < 22; ++i) m = fmaxf(m, t[i]);
    float p[22]; float s = 0.0f;
    #pragma unroll
    for (int i = 0; i < 22; ++i) { p[i] = __expf(t[i] - m); s += p[i]; }
    float scale = sw / s;

    float* oa = zout + (size_t)a * kZrow;
    float* ob = zout + (size_t)b * kZrow;
    #pragma unroll
    for (int i = 0; i < 10; ++i)
        unsafeAtomicAdd(oa + i, ((i & 1) ? -scale : scale) * p[i]);
    #pragma unroll
    for (int i = 0; i < 10; ++i)
        unsafeAtomicAdd(ob + i, ((i & 1) ? -scale : scale) * p[10 + i]);
}

// ---------------------------------------------------------------------------
extern "C" void kernel_launch(void* const* d_in, const int* in_sizes, int n_in,
                              void* d_out, int out_size, void* d_ws, size_t ws_size,
                              hipStream_t stream)
{
    const float* feat = (const float*)d_in[0];
    const float* rel  = (const float*)d_in[1];
    const float* W1   = (const float*)d_in[2];
    const float* b1   = (const float*)d_in[3];
    const float* W2   = (const float*)d_in[4];
    const float* b2   = (const float*)d_in[5];
    const float* cw   = (const float*)d_in[6];
    const int*   sx   = (const int*)d_in[7];
    const int*   sy   = (const int*)d_in[8];
    float* out = (float*)d_out;

    // ws layout (all offsets 128B-aligned)
    char* ws = (char*)d_ws;
    const size_t off_zA     = 0;                       // 4,800,000
    const size_t off_zB     = 4800000;                 // 4,800,000
    const size_t off_gcur   = 9600000;                 // 512
    const size_t off_rowptr = 9600512;                 // 400,384
    const size_t off_rowcnt = 10000896;                // 400,384
    const size_t off_bkey   = 10401280;                // 98*70000*4  = 27,440,000
    const size_t off_brel   = 37841280;                // 98*70000*8  = 54,880,000
    const size_t off_skey   = 92721280;                // 27,440,000
    const size_t off_srel   = 120161280;               // 54,880,000
    const size_t need_csr   = 175041280;               // ~175 MB
    const size_t off_part   = off_skey;                // fallback A partials: 98*10*40960
    const size_t need_p2    = off_skey + (size_t)kCB * kSplit * kCBNodes * 10 * 4; // ~132.9 MB

    float*    zA     = (float*)(ws + off_zA);
    float*    zB     = (float*)(ws + off_zB);
    int*      gcur   = (int*)(ws + off_gcur);
    int*      rowptr = (int*)(ws + off_rowptr);
    int*      rowcnt = (int*)(ws + off_rowcnt);
    unsigned* bkey   = (unsigned*)(ws + off_bkey);
    float2*   brel   = (float2*)(ws + off_brel);
    unsigned* skey   = (unsigned*)(ws + off_skey);
    float2*   srel   = (float2*)(ws + off_srel);
    float*    partials = (float*)(ws + off_part);

    dim3 blk(256);
    dim3 gN((kN + 255) / 256);
    dim3 gE((kE + 255) / 256);
    dim3 gB((kE + kChunkE - 1) / kChunkE);
    dim3 gG(kN / 16);                       // 6250

    mlp_kernel<<<gN, blk, 0, stream>>>(feat, W1, b1, W2, b2, zA);

    if (ws_size >= need_csr) {
        hipMemsetAsync(gcur, 0, 512, stream);
        bucketize<<<gB, blk, 0, stream>>>(sx, sy, rel, gcur, bkey, brel);
        sort_bucket<<<dim3(kCB), dim3(1024), 0, stream>>>(gcur, bkey, brel,
                                                          skey, srel, rowptr, rowcnt);
        kenn_gather_csr<<<gG, blk, 0, stream>>>(zA, zB, skey, srel, rowptr, rowcnt, cw, 0);
        kenn_gather_csr<<<gG, blk, 0, stream>>>(zB, zA, skey, srel, rowptr, rowcnt, cw, 1);
        kenn_gather_csr<<<gG, blk, 0, stream>>>(zA, zB, skey, srel, rowptr, rowcnt, cw, 2);
        out_kernel<<<gN, blk, 0, stream>>>(zB, out);
    } else if (ws_size >= need_p2) {
        hipMemsetAsync(gcur, 0, 512, stream);
        bucketize<<<gB, blk, 0, stream>>>(sx, sy, rel, gcur, bkey, brel);
        dim3 gP(kCB * kSplit);
        kenn_gather_part<<<gP, blk, 0, stream>>>(zA, gcur, bkey, brel, cw, 0, partials);
        kenn_reduce<<<gN, blk, 0, stream>>>(zA, zB, partials);
        kenn_gather_part<<<gP, blk, 0, stream>>>(zB, gcur, bkey, brel, cw, 1, partials);
        kenn_reduce<<<gN, blk, 0, stream>>>(zB, zA, partials);
        kenn_gather_part<<<gP, blk, 0, stream>>>(zA, gcur, bkey, brel, cw, 2, partials);
        kenn_reduce<<<gN, blk, 0, stream>>>(zA, zB, partials);
        out_kernel<<<gN, blk, 0, stream>>>(zB, out);
    } else {
        size_t zbytes = (size_t)kN * kZrow * sizeof(float);
        hipMemcpyAsync(zB, zA, zbytes, hipMemcpyDeviceToDevice, stream);
        edge_kernel<<<gE, blk, 0, stream>>>(zA, zB, rel, sx, sy, cw, 0);
        hipMemcpyAsync(zA, zB, zbytes, hipMemcpyDeviceToDevice, stream);
        edge_kernel<<<gE, blk, 0, stream>>>(zB, zA, rel, sx, sy, cw, 1);
        hipMemcpyAsync(zB, zA, zbytes, hipMemcpyDeviceToDevice, stream);
        edge_kernel<<<gE, blk, 0, stream>>>(zA, zB, rel, sx, sy, cw, 2);
        out_kernel<<<gN, blk, 0, stream>>>(zB, out);
    }
}

// Round 7
// 686.551 us; speedup vs baseline: 2.2970x; 1.1050x over previous
//
#include <hip/hip_runtime.h>
#include <math.h>

constexpr int kN    = 100000;
constexpr int kE    = 3200000;
constexpr int kHid  = 1024;
constexpr int kZrow = 12;

// coarse buckets: 1024 nodes each
constexpr int kCBShift = 10;
constexpr int kCBNodes = 1 << kCBShift;                    // 1024
constexpr int kCB      = (kN + kCBNodes - 1) / kCBNodes;   // 98
constexpr int kCBCap   = 68000;                            // mean 65536, +9.7 sigma
constexpr int kChunkE  = 1024;                             // edges per bucketize block
constexpr int kChunkEnt= kChunkE * 2;

// key layout: partner[16:0] | own_local[26:17] | side[27]

// ---------------------------------------------------------------------------
// Kernel 1: per-node MLP + derived columns.
// ---------------------------------------------------------------------------
__global__ __launch_bounds__(256) void mlp_kernel(
    const float* __restrict__ feat,
    const float* __restrict__ W1,
    const float* __restrict__ b1,
    const float* __restrict__ W2,
    const float* __restrict__ b2,
    float* __restrict__ z)
{
    int n = blockIdx.x * blockDim.x + threadIdx.x;
    if (n >= kN) return;

    const float4* fr = reinterpret_cast<const float4*>(feat + (size_t)n * 12);
    float4 f0 = fr[0], f1 = fr[1], f2 = fr[2];
    float f[12] = {f0.x, f0.y, f0.z, f0.w,
                   f1.x, f1.y, f1.z, f1.w,
                   f2.x, f2.y, f2.z, f2.w};

    float acc[8];
    #pragma unroll
    for (int o = 0; o < 8; ++o) acc[o] = b2[o];

    #pragma unroll 4
    for (int k = 0; k < kHid; ++k) {
        float h = b1[k];
        #pragma unroll
        for (int d = 0; d < 12; ++d) h = fmaf(f[d], W1[d * kHid + k], h);
        h = fmaxf(h, 0.0f);
        #pragma unroll
        for (int o = 0; o < 8; ++o) acc[o] = fmaf(h, W2[k * 8 + o], acc[o]);
    }

    float ymin_diff = (f[2] - f[10]) * 10.0f;
    bool mask = (f[0] <= f[5]) && (f[1] >= f[4]) &&
                (f[2] <= f[11]) && (f[3] >= f[10]);
    float inter = mask ? 5.0f : -5.0f;

    float* zr = z + (size_t)n * kZrow;
    reinterpret_cast<float4*>(zr)[0] = {acc[0], acc[1], acc[2], acc[3]};
    reinterpret_cast<float4*>(zr)[1] = {acc[4], acc[5], acc[6], acc[7]};
    reinterpret_cast<float4*>(zr)[2] = {ymin_diff, inter, 0.0f, 0.0f};
}

// ---------------------------------------------------------------------------
// Kernel 2: bucketize incidences into 98 coarse buckets (SoA, rel embedded).
// ---------------------------------------------------------------------------
__global__ __launch_bounds__(256) void bucketize(
    const int* __restrict__ sx,
    const int* __restrict__ sy,
    const float* __restrict__ rel,
    int* __restrict__ gcur,
    unsigned* __restrict__ bkey,
    float2* __restrict__ brel)
{
    __shared__ int      cnt[128];
    __shared__ int      scn[128];
    __shared__ int      startArr[129];
    __shared__ int      c2[128];
    __shared__ int      gbase[128];
    __shared__ unsigned stage_k[kChunkEnt];
    __shared__ float2   stage_r[kChunkEnt];

    int tid  = threadIdx.x;
    int e0   = blockIdx.x * kChunkE;
    int ecnt = min(kChunkE, kE - e0);

    if (tid < 128) cnt[tid] = 0;
    __syncthreads();

    int ea[kChunkE / 256], eb[kChunkE / 256];
    int ne = 0;
    for (int i = tid; i < ecnt; i += 256) {
        int a = sx[e0 + i];
        int b = sy[e0 + i];
        ea[ne] = a; eb[ne] = b; ++ne;
        atomicAdd(&cnt[a >> kCBShift], 1);
        atomicAdd(&cnt[b >> kCBShift], 1);
    }
    __syncthreads();

    if (tid < 128) scn[tid] = cnt[tid];
    __syncthreads();
    for (int off = 1; off < 128; off <<= 1) {
        int v = 0;
        if (tid < 128 && tid >= off) v = scn[tid - off];
        __syncthreads();
        if (tid < 128) scn[tid] += v;
        __syncthreads();
    }
    if (tid < 128) startArr[tid] = scn[tid] - cnt[tid];
    if (tid == 127) startArr[128] = scn[127];
    __syncthreads();

    if (tid < 128) {
        int c = (tid < kCB) ? cnt[tid] : 0;
        gbase[tid] = (c > 0) ? atomicAdd(&gcur[tid], c) : 0;
        c2[tid] = startArr[tid];
    }
    __syncthreads();

    ne = 0;
    for (int i = tid; i < ecnt; i += 256) {
        int a = ea[ne], b = eb[ne]; ++ne;
        float2 r = reinterpret_cast<const float2*>(rel)[e0 + i];
        int sa = atomicAdd(&c2[a >> kCBShift], 1);
        stage_k[sa] = (unsigned)b | ((unsigned)(a & (kCBNodes - 1)) << 17);
        stage_r[sa] = r;
        int sb = atomicAdd(&c2[b >> kCBShift], 1);
        stage_k[sb] = (unsigned)a | ((unsigned)(b & (kCBNodes - 1)) << 17) | (1u << 27);
        stage_r[sb] = r;
    }
    __syncthreads();

    int total = 2 * ecnt;
    for (int j = tid; j < total; j += 256) {
        int lo = 0, hi = kCB;
        while (hi - lo > 1) {
            int mid = (lo + hi) >> 1;
            if (startArr[mid] <= j) lo = mid; else hi = mid;
        }
        int idx = gbase[lo] + (j - startArr[lo]);
        if (idx < kCBCap) {
            size_t dst = (size_t)lo * kCBCap + idx;
            bkey[dst] = stage_k[j];
            brel[dst] = stage_r[j];
        }
    }
}

// ---------------------------------------------------------------------------
// Kernel 3 (tier1): counting-sort one bucket -> CSR, ONE 16B scatter/entry.
// ---------------------------------------------------------------------------
__global__ __launch_bounds__(1024) void sort_bucket16(
    const int* __restrict__ gcur,
    const unsigned* __restrict__ bkey,
    const float2* __restrict__ brel,
    uint4* __restrict__ sdata,
    int* __restrict__ rowptr,
    int* __restrict__ rowcnt)
{
    __shared__ int cnt1024[kCBNodes];
    __shared__ int scanb[kCBNodes];
    __shared__ int cur[kCBNodes];

    int tid = threadIdx.x;
    int b   = blockIdx.x;
    int n   = min(gcur[b], kCBCap);
    const unsigned* bk = bkey + (size_t)b * kCBCap;
    const float2*   br = brel + (size_t)b * kCBCap;

    cnt1024[tid] = 0;
    __syncthreads();

    for (int j = tid; j < n; j += 1024)
        atomicAdd(&cnt1024[(bk[j] >> 17) & 1023u], 1);
    __syncthreads();

    scanb[tid] = cnt1024[tid];
    __syncthreads();
    for (int off = 1; off < kCBNodes; off <<= 1) {
        int v = (tid >= off) ? scanb[tid - off] : 0;
        __syncthreads();
        scanb[tid] += v;
        __syncthreads();
    }
    int excl = scanb[tid] - cnt1024[tid];
    cur[tid] = excl;

    int node = (b << kCBShift) + tid;
    if (node < kN) {
        rowptr[node] = b * kCBCap + excl;
        rowcnt[node] = cnt1024[tid];
    }
    __syncthreads();

    for (int j = tid; j < n; j += 1024) {
        unsigned k = bk[j];
        float2  r  = br[j];
        int ol = (int)((k >> 17) & 1023u);
        int pos = atomicAdd(&cur[ol], 1);
        sdata[(size_t)b * kCBCap + pos] =
            make_uint4(k, __float_as_uint(r.x), __float_as_uint(r.y), 0u);
    }
}

// ---------------------------------------------------------------------------
// Kernel 4 (tier1): gather layer from 16B entries, register accumulation.
// ---------------------------------------------------------------------------
__global__ __launch_bounds__(256) void gather16(
    const float* __restrict__ zin,
    float* __restrict__ zout,
    const uint4* __restrict__ sdata,
    const int* __restrict__ rowptr,
    const int* __restrict__ rowcnt,
    const float* __restrict__ cw,
    int layer)
{
    int node = blockIdx.x * 16 + (threadIdx.x >> 4);
    int lane = threadIdx.x & 15;
    if (node >= kN) return;

    float w  = cw[layer];
    float sw = fmaxf(w, 0.0f) + log1pf(__expf(-fabsf(w)));  // softplus

    const float* zs = zin + (size_t)node * kZrow;
    float4 s0 = reinterpret_cast<const float4*>(zs)[0];
    float4 s1 = reinterpret_cast<const float4*>(zs)[1];
    float4 s2 = reinterpret_cast<const float4*>(zs)[2];
    float self[10] = {s0.x, s0.y, s0.z, s0.w, s1.x, s1.y, s1.z, s1.w, s2.x, s2.y};

    float acc[10] = {0,0,0,0,0,0,0,0,0,0};
    int rp = rowptr[node];
    int rc = rowcnt[node];

    for (int i = lane; i < rc; i += 16) {
        uint4 ent = sdata[rp + i];
        unsigned k = ent.x;
        float rx = __uint_as_float(ent.y);
        float ry = __uint_as_float(ent.z);
        int p    = (int)(k & 0x1FFFFu);
        int side = (int)((k >> 27) & 1u);

        const float* zp = zin + (size_t)p * kZrow;
        float4 p0 = reinterpret_cast<const float4*>(zp)[0];
        float4 p1 = reinterpret_cast<const float4*>(zp)[1];
        float2 p2 = reinterpret_cast<const float2*>(zp + 8)[0];
        float part[10] = {p0.x, p0.y, p0.z, p0.w, p1.x, p1.y, p1.z, p1.w, p2.x, p2.y};

        float t[22];
        #pragma unroll
        for (int j = 0; j < 10; ++j) {
            float ga = side ? part[j] : self[j];
            float gb = side ? self[j] : part[j];
            t[j]      = (j & 1) ? -ga : ga;
            t[10 + j] = (j & 1) ? -gb : gb;
        }
        t[20] = rx;
        t[21] = -ry;

        float m = t[0];
        #pragma unroll
        for (int j = 1; j < 22; ++j) m = fmaxf(m, t[j]);

        float pe[22];
        float ssum = 0.0f;
        #pragma unroll
        for (int j = 0; j < 22; ++j) { pe[j] = __expf(t[j] - m); ssum += pe[j]; }

        float scale = sw / ssum;
        #pragma unroll
        for (int j = 0; j < 10; ++j) {
            float pv = side ? pe[10 + j] : pe[j];
            acc[j] += ((j & 1) ? -scale : scale) * pv;
        }
    }

    #pragma unroll
    for (int m16 = 8; m16 >= 1; m16 >>= 1) {
        #pragma unroll
        for (int j = 0; j < 10; ++j)
            acc[j] += __shfl_xor(acc[j], m16, 16);
    }

    if (lane == 0) {
        float* zo = zout + (size_t)node * kZrow;
        reinterpret_cast<float4*>(zo)[0] =
            {self[0] + acc[0], self[1] + acc[1], self[2] + acc[2], self[3] + acc[3]};
        reinterpret_cast<float4*>(zo)[1] =
            {self[4] + acc[4], self[5] + acc[5], self[6] + acc[6], self[7] + acc[7]};
        reinterpret_cast<float4*>(zo)[2] =
            {self[8] + acc[8], self[9] + acc[9], s2.z, s2.w};
    }
}

// ---------------------------------------------------------------------------
// Kernel 5 (tier1): final gather layer fused with output heads.
// Only cols 0..7 are needed downstream -> skip acc[8..9], write out directly.
// ---------------------------------------------------------------------------
__global__ __launch_bounds__(256) void gather16_out(
    const float* __restrict__ zin,
    float* __restrict__ out,
    const uint4* __restrict__ sdata,
    const int* __restrict__ rowptr,
    const int* __restrict__ rowcnt,
    const float* __restrict__ cw,
    int layer)
{
    int node = blockIdx.x * 16 + (threadIdx.x >> 4);
    int lane = threadIdx.x & 15;
    if (node >= kN) return;

    float w  = cw[layer];
    float sw = fmaxf(w, 0.0f) + log1pf(__expf(-fabsf(w)));

    const float* zs = zin + (size_t)node * kZrow;
    float4 s0 = reinterpret_cast<const float4*>(zs)[0];
    float4 s1 = reinterpret_cast<const float4*>(zs)[1];
    float4 s2 = reinterpret_cast<const float4*>(zs)[2];
    float self[10] = {s0.x, s0.y, s0.z, s0.w, s1.x, s1.y, s1.z, s1.w, s2.x, s2.y};

    float acc[8] = {0,0,0,0,0,0,0,0};
    int rp = rowptr[node];
    int rc = rowcnt[node];

    for (int i = lane; i < rc; i += 16) {
        uint4 ent = sdata[rp + i];
        unsigned k = ent.x;
        float rx = __uint_as_float(ent.y);
        float ry = __uint_as_float(ent.z);
        int p    = (int)(k & 0x1FFFFu);
        int side = (int)((k >> 27) & 1u);

        const float* zp = zin + (size_t)p * kZrow;
        float4 p0 = reinterpret_cast<const float4*>(zp)[0];
        float4 p1 = reinterpret_cast<const float4*>(zp)[1];
        float2 p2 = reinterpret_cast<const float2*>(zp + 8)[0];
        float part[10] = {p0.x, p0.y, p0.z, p0.w, p1.x, p1.y, p1.z, p1.w, p2.x, p2.y};

        float t[22];
        #pragma unroll
        for (int j = 0; j < 10; ++j) {
            float ga = side ? part[j] : self[j];
            float gb = side ? self[j] : part[j];
            t[j]      = (j & 1) ? -ga : ga;
            t[10 + j] = (j & 1) ? -gb : gb;
        }
        t[20] = rx;
        t[21] = -ry;

        float m = t[0];
        #pragma unroll
        for (int j = 1; j < 22; ++j) m = fmaxf(m, t[j]);

        float pe[22];
        float ssum = 0.0f;
        #pragma unroll
        for (int j = 0; j < 22; ++j) { pe[j] = __expf(t[j] - m); ssum += pe[j]; }

        float scale = sw / ssum;
        #pragma unroll
        for (int j = 0; j < 8; ++j) {
            float pv = side ? pe[10 + j] : pe[j];
            acc[j] += ((j & 1) ? -scale : scale) * pv;
        }
    }

    #pragma unroll
    for (int m16 = 8; m16 >= 1; m16 >>= 1) {
        #pragma unroll
        for (int j = 0; j < 8; ++j)
            acc[j] += __shfl_xor(acc[j], m16, 16);
    }

    if (lane == 0) {
        float4 za = {self[0] + acc[0], self[1] + acc[1], self[2] + acc[2], self[3] + acc[3]};
        float4 zb = {self[4] + acc[4], self[5] + acc[5], self[6] + acc[6], self[7] + acc[7]};

        float ma = fmaxf(fmaxf(za.x, za.y), fmaxf(za.z, za.w));
        float ea0 = __expf(za.x - ma), ea1 = __expf(za.y - ma);
        float ea2 = __expf(za.z - ma), ea3 = __expf(za.w - ma);
        float ia = 1.0f / (ea0 + ea1 + ea2 + ea3);
        float4 sma = {ea0 * ia, ea1 * ia, ea2 * ia, ea3 * ia};

        float mb = fmaxf(fmaxf(zb.x, zb.y), fmaxf(zb.z, zb.w));
        float eb0 = __expf(zb.x - mb), eb1 = __expf(zb.y - mb);
        float eb2 = __expf(zb.z - mb), eb3 = __expf(zb.w - mb);
        float ib = 1.0f / (eb0 + eb1 + eb2 + eb3);
        float4 smb = {eb0 * ib, eb1 * ib, eb2 * ib, eb3 * ib};

        reinterpret_cast<float4*>(out)[node]           = za;
        reinterpret_cast<float4*>(out + 4 * kN)[node]  = sma;
        reinterpret_cast<float4*>(out + 8 * kN)[node]  = zb;
        reinterpret_cast<float4*>(out + 12 * kN)[node] = smb;
    }
}

// ---------------------------------------------------------------------------
// Tier2 (R6-proven): split-stream sort + gather + out.
// ---------------------------------------------------------------------------
__global__ __launch_bounds__(1024) void sort_bucket(
    const int* __restrict__ gcur,
    const unsigned* __restrict__ bkey,
    const float2* __restrict__ brel,
    unsigned* __restrict__ skey,
    float2* __restrict__ srel,
    int* __restrict__ rowptr,
    int* __restrict__ rowcnt)
{
    __shared__ int cnt1024[kCBNodes];
    __shared__ int scanb[kCBNodes];
    __shared__ int cur[kCBNodes];

    int tid = threadIdx.x;
    int b   = blockIdx.x;
    int n   = min(gcur[b], kCBCap);
    const unsigned* bk = bkey + (size_t)b * kCBCap;
    const float2*   br = brel + (size_t)b * kCBCap;

    cnt1024[tid] = 0;
    __syncthreads();
    for (int j = tid; j < n; j += 1024)
        atomicAdd(&cnt1024[(bk[j] >> 17) & 1023u], 1);
    __syncthreads();

    scanb[tid] = cnt1024[tid];
    __syncthreads();
    for (int off = 1; off < kCBNodes; off <<= 1) {
        int v = (tid >= off) ? scanb[tid - off] : 0;
        __syncthreads();
        scanb[tid] += v;
        __syncthreads();
    }
    int excl = scanb[tid] - cnt1024[tid];
    cur[tid] = excl;

    int node = (b << kCBShift) + tid;
    if (node < kN) {
        rowptr[node] = b * kCBCap + excl;
        rowcnt[node] = cnt1024[tid];
    }
    __syncthreads();

    for (int j = tid; j < n; j += 1024) {
        unsigned k = bk[j];
        float2  r  = br[j];
        int ol = (int)((k >> 17) & 1023u);
        int pos = atomicAdd(&cur[ol], 1);
        size_t dst = (size_t)b * kCBCap + pos;
        skey[dst] = k;
        srel[dst] = r;
    }
}

__global__ __launch_bounds__(256) void kenn_gather_csr(
    const float* __restrict__ zin,
    float* __restrict__ zout,
    const unsigned* __restrict__ skey,
    const float2* __restrict__ srel,
    const int* __restrict__ rowptr,
    const int* __restrict__ rowcnt,
    const float* __restrict__ cw,
    int layer)
{
    int node = blockIdx.x * 16 + (threadIdx.x >> 4);
    int lane = threadIdx.x & 15;
    if (node >= kN) return;

    float w  = cw[layer];
    float sw = fmaxf(w, 0.0f) + log1pf(__expf(-fabsf(w)));

    const float* zs = zin + (size_t)node * kZrow;
    float4 s0 = reinterpret_cast<const float4*>(zs)[0];
    float4 s1 = reinterpret_cast<const float4*>(zs)[1];
    float4 s2 = reinterpret_cast<const float4*>(zs)[2];
    float self[10] = {s0.x, s0.y, s0.z, s0.w, s1.x, s1.y, s1.z, s1.w, s2.x, s2.y};

    float acc[10] = {0,0,0,0,0,0,0,0,0,0};
    int rp = rowptr[node];
    int rc = rowcnt[node];

    for (int i = lane; i < rc; i += 16) {
        unsigned k = skey[rp + i];
        float2  r  = srel[rp + i];
        int p    = (int)(k & 0x1FFFFu);
        int side = (int)((k >> 27) & 1u);

        const float* zp = zin + (size_t)p * kZrow;
        float4 p0 = reinterpret_cast<const float4*>(zp)[0];
        float4 p1 = reinterpret_cast<const float4*>(zp)[1];
        float2 p2 = reinterpret_cast<const float2*>(zp + 8)[0];
        float part[10] = {p0.x, p0.y, p0.z, p0.w, p1.x, p1.y, p1.z, p1.w, p2.x, p2.y};

        float t[22];
        #pragma unroll
        for (int j = 0; j < 10; ++j) {
            float ga = side ? part[j] : self[j];
            float gb = side ? self[j] : part[j];
            t[j]      = (j & 1) ? -ga : ga;
            t[10 + j] = (j & 1) ? -gb : gb;
        }
        t[20] = r.x;
        t[21] = -r.y;

        float m = t[0];
        #pragma unroll
        for (int j = 1; j < 22; ++j) m = fmaxf(m, t[j]);

        float pe[22];
        float ssum = 0.0f;
        #pragma unroll
        for (int j = 0; j < 22; ++j) { pe[j] = __expf(t[j] - m); ssum += pe[j]; }

        float scale = sw / ssum;
        #pragma unroll
        for (int j = 0; j < 10; ++j) {
            float pv = side ? pe[10 + j] : pe[j];
            acc[j] += ((j & 1) ? -scale : scale) * pv;
        }
    }

    #pragma unroll
    for (int m16 = 8; m16 >= 1; m16 >>= 1) {
        #pragma unroll
        for (int j = 0; j < 10; ++j)
            acc[j] += __shfl_xor(acc[j], m16, 16);
    }

    if (lane == 0) {
        float* zo = zout + (size_t)node * kZrow;
        reinterpret_cast<float4*>(zo)[0] =
            {self[0] + acc[0], self[1] + acc[1], self[2] + acc[2], self[3] + acc[3]};
        reinterpret_cast<float4*>(zo)[1] =
            {self[4] + acc[4], self[5] + acc[5], self[6] + acc[6], self[7] + acc[7]};
        reinterpret_cast<float4*>(zo)[2] =
            {self[8] + acc[8], self[9] + acc[9], s2.z, s2.w};
    }
}

__global__ __launch_bounds__(256) void out_kernel(
    const float* __restrict__ z,
    float* __restrict__ out)
{
    int n = blockIdx.x * blockDim.x + threadIdx.x;
    if (n >= kN) return;

    const float* zr = z + (size_t)n * kZrow;
    float4 za = reinterpret_cast<const float4*>(zr)[0];
    float4 zb = reinterpret_cast<const float4*>(zr)[1];

    float ma = fmaxf(fmaxf(za.x, za.y), fmaxf(za.z, za.w));
    float ea0 = __expf(za.x - ma), ea1 = __expf(za.y - ma);
    float ea2 = __expf(za.z - ma), ea3 = __expf(za.w - ma);
    float ia = 1.0f / (ea0 + ea1 + ea2 + ea3);
    float4 sma = {ea0 * ia, ea1 * ia, ea2 * ia, ea3 * ia};

    float mb = fmaxf(fmaxf(zb.x, zb.y), fmaxf(zb.z, zb.w));
    float eb0 = __expf(zb.x - mb), eb1 = __expf(zb.y - mb);
    float eb2 = __expf(zb.z - mb), eb3 = __expf(zb.w - mb);
    float ib = 1.0f / (eb0 + eb1 + eb2 + eb3);
    float4 smb = {eb0 * ib, eb1 * ib, eb2 * ib, eb3 * ib};

    reinterpret_cast<float4*>(out)[n]           = za;
    reinterpret_cast<float4*>(out + 4 * kN)[n]  = sma;
    reinterpret_cast<float4*>(out + 8 * kN)[n]  = zb;
    reinterpret_cast<float4*>(out + 12 * kN)[n] = smb;
}

// ---------------------------------------------------------------------------
// Tier3 (R1-proven): atomic scatter, minimal ws.
// ---------------------------------------------------------------------------
__global__ __launch_bounds__(256) void edge_kernel(
    const float* __restrict__ zin,
    float* __restrict__ zout,
    const float* __restrict__ rel,
    const int* __restrict__ sx,
    const int* __restrict__ sy,
    const float* __restrict__ cw,
    int layer)
{
    int e = blockIdx.x * blockDim.x + threadIdx.x;
    if (e >= kE) return;

    float w  = cw[layer];
    float sw = fmaxf(w, 0.0f) + log1pf(__expf(-fabsf(w)));

    int a = sx[e];
    int b = sy[e];
    float2 r = reinterpret_cast<const float2*>(rel)[e];

    const float* za = zin + (size_t)a * kZrow;
    const float* zb = zin + (size_t)b * kZrow;
    float4 a0 = reinterpret_cast<const float4*>(za)[0];
    float4 a1 = reinterpret_cast<const float4*>(za)[1];
    float2 a2 = reinterpret_cast<const float2*>(za + 8)[0];
    float4 b0 = reinterpret_cast<const float4*>(zb)[0];
    float4 b1v = reinterpret_cast<const float4*>(zb)[1];
    float2 b2v = reinterpret_cast<const float2*>(zb + 8)[0];

    float t[22];
    t[0]  =  a0.x;  t[1]  = -a0.y;  t[2]  =  a0.z;  t[3]  = -a0.w;
    t[4]  =  a1.x;  t[5]  = -a1.y;  t[6]  =  a1.z;  t[7]  = -a1.w;
    t[8]  =  a2.x;  t[9]  = -a2.y;
    t[10] =  b0.x;  t[11] = -b0.y;  t[12] =  b0.z;  t[13] = -b0.w;
    t[14] =  b1v.x; t[15] = -b1v.y; t[16] =  b1v.z; t[17] = -b1v.w;
    t[18] =  b2v.x; t[19] = -b2v.y;
    t[20] =  r.x;   t[21] = -r.y;

    float m = t[0];
    #pragma unroll
    for (int i = 1; i < 22; ++i) m = fmaxf(m, t[i]);
    float p[22]; float s = 0.0f;
    #pragma unroll
    for (int i = 0; i < 22; ++i) { p[i] = __expf(t[i] - m); s += p[i]; }
    float scale = sw / s;

    float* oa = zout + (size_t)a * kZrow;
    float* ob = zout + (size_t)b * kZrow;
    #pragma unroll
    for (int i = 0; i < 10; ++i)
        unsafeAtomicAdd(oa + i, ((i & 1) ? -scale : scale) * p[i]);
    #pragma unroll
    for (int i = 0; i < 10; ++i)
        unsafeAtomicAdd(ob + i, ((i & 1) ? -scale : scale) * p[10 + i]);
}

// ---------------------------------------------------------------------------
extern "C" void kernel_launch(void* const* d_in, const int* in_sizes, int n_in,
                              void* d_out, int out_size, void* d_ws, size_t ws_size,
                              hipStream_t stream)
{
    const float* feat = (const float*)d_in[0];
    const float* rel  = (const float*)d_in[1];
    const float* W1   = (const float*)d_in[2];
    const float* b1   = (const float*)d_in[3];
    const float* W2   = (const float*)d_in[4];
    const float* b2   = (const float*)d_in[5];
    const float* cw   = (const float*)d_in[6];
    const int*   sx   = (const int*)d_in[7];
    const int*   sy   = (const int*)d_in[8];
    float* out = (float*)d_out;

    // ws layout (bytes)
    char* ws = (char*)d_ws;
    const size_t off_zA     = 0;                        // 4,800,000
    const size_t off_zB     = 4800000;                  // 4,800,000
    const size_t off_gcur   = 9600000;                  // 512
    const size_t off_rowptr = 9600512;                  // 400,384
    const size_t off_rowcnt = 10000896;                 // 400,384
    const size_t off_bkey   = 10401280;                 // 98*68000*4  = 26,656,000
    const size_t off_brel   = 37057280;                 // 98*68000*8  = 53,312,000
    const size_t off_sdata  = 90369280;                 // 98*68000*16 = 106,624,000
    const size_t need_t1    = 196993280;                // ~197 MB
    const size_t off_skey   = off_sdata;                // tier2: 26,656,000
    const size_t off_srel   = 117025280;                // tier2: 53,312,000
    const size_t need_t2    = 170337280;                // ~170 MB (proven <= ws)

    float*    zA     = (float*)(ws + off_zA);
    float*    zB     = (float*)(ws + off_zB);
    int*      gcur   = (int*)(ws + off_gcur);
    int*      rowptr = (int*)(ws + off_rowptr);
    int*      rowcnt = (int*)(ws + off_rowcnt);
    unsigned* bkey   = (unsigned*)(ws + off_bkey);
    float2*   brel   = (float2*)(ws + off_brel);
    uint4*    sdata  = (uint4*)(ws + off_sdata);
    unsigned* skey   = (unsigned*)(ws + off_skey);
    float2*   srel   = (float2*)(ws + off_srel);

    dim3 blk(256);
    dim3 gN((kN + 255) / 256);
    dim3 gE((kE + 255) / 256);
    dim3 gB((kE + kChunkE - 1) / kChunkE);
    dim3 gG(kN / 16);                       // 6250

    mlp_kernel<<<gN, blk, 0, stream>>>(feat, W1, b1, W2, b2, zA);

    if (ws_size >= need_t1) {
        hipMemsetAsync(gcur, 0, 512, stream);
        bucketize<<<gB, blk, 0, stream>>>(sx, sy, rel, gcur, bkey, brel);
        sort_bucket16<<<dim3(kCB), dim3(1024), 0, stream>>>(gcur, bkey, brel,
                                                            sdata, rowptr, rowcnt);
        gather16<<<gG, blk, 0, stream>>>(zA, zB, sdata, rowptr, rowcnt, cw, 0);
        gather16<<<gG, blk, 0, stream>>>(zB, zA, sdata, rowptr, rowcnt, cw, 1);
        gather16_out<<<gG, blk, 0, stream>>>(zA, out, sdata, rowptr, rowcnt, cw, 2);
    } else if (ws_size >= need_t2) {
        hipMemsetAsync(gcur, 0, 512, stream);
        bucketize<<<gB, blk, 0, stream>>>(sx, sy, rel, gcur, bkey, brel);
        sort_bucket<<<dim3(kCB), dim3(1024), 0, stream>>>(gcur, bkey, brel,
                                                          skey, srel, rowptr, rowcnt);
        kenn_gather_csr<<<gG, blk, 0, stream>>>(zA, zB, skey, srel, rowptr, rowcnt, cw, 0);
        kenn_gather_csr<<<gG, blk, 0, stream>>>(zB, zA, skey, srel, rowptr, rowcnt, cw, 1);
        kenn_gather_csr<<<gG, blk, 0, stream>>>(zA, zB, skey, srel, rowptr, rowcnt, cw, 2);
        out_kernel<<<gN, blk, 0, stream>>>(zB, out);
    } else {
        size_t zbytes = (size_t)kN * kZrow * sizeof(float);
        hipMemcpyAsync(zB, zA, zbytes, hipMemcpyDeviceToDevice, stream);
        edge_kernel<<<gE, blk, 0, stream>>>(zA, zB, rel, sx, sy, cw, 0);
        hipMemcpyAsync(zA, zB, zbytes, hipMemcpyDeviceToDevice, stream);
        edge_kernel<<<gE, blk, 0, stream>>>(zB, zA, rel, sx, sy, cw, 1);
        hipMemcpyAsync(zB, zA, zbytes, hipMemcpyDeviceToDevice, stream);
        edge_kernel<<<gE, blk, 0, stream>>>(zA, zB, rel, sx, sy, cw, 2);
        out_kernel<<<gN, blk, 0, stream>>>(zB, out);
    }
}

// Round 9
// 590.969 us; speedup vs baseline: 2.6685x; 1.1617x over previous
//
#include <hip/hip_runtime.h>
#include <math.h>

constexpr int kN    = 100000;
constexpr int kE    = 3200000;
constexpr int kHid  = 1024;
constexpr int kZrow = 12;

// coarse buckets: 1024 nodes each
constexpr int kCBShift = 10;
constexpr int kCBNodes = 1 << kCBShift;                    // 1024
constexpr int kCB      = (kN + kCBNodes - 1) / kCBNodes;   // 98
constexpr int kCBCap   = 68000;                            // mean 65536, +9.7 sigma
constexpr int kChunkE  = 1024;                             // edges per bucketize block
constexpr int kChunkEnt= kChunkE * 2;

// key layout: partner[16:0] | own_local[26:17] | side[27]

// ---------------------------------------------------------------------------
// Kernel 1: per-node MLP + derived columns. 4 waves split the 1024 hidden
// units of 64 nodes; LDS reduce. Raises occupancy 19% -> ~76% (100K threads
// was the R7 ceiling: OccupancyPercent 17.9, VALUBusy 25.7).
// ---------------------------------------------------------------------------
__global__ __launch_bounds__(256) void mlp_kernel4(
    const float* __restrict__ feat,
    const float* __restrict__ W1,
    const float* __restrict__ b1,
    const float* __restrict__ W2,
    const float* __restrict__ b2,
    float* __restrict__ z)
{
    __shared__ float red[4][8][64];          // [wave][out][node-lane], 8 KB

    int wave = (int)__builtin_amdgcn_readfirstlane(threadIdx.x >> 6); // SGPR k-chunk
    int lane = threadIdx.x & 63;
    int n    = blockIdx.x * 64 + lane;
    bool valid = n < kN;
    int nc   = valid ? n : (kN - 1);         // clamp to avoid OOB loads

    const float4* fr = reinterpret_cast<const float4*>(feat + (size_t)nc * 12);
    float4 f0 = fr[0], f1 = fr[1], f2 = fr[2];
    float f[12] = {f0.x, f0.y, f0.z, f0.w,
                   f1.x, f1.y, f1.z, f1.w,
                   f2.x, f2.y, f2.z, f2.w};

    float acc[8] = {0,0,0,0,0,0,0,0};
    int k0 = wave * (kHid / 4);
    int k1 = k0 + (kHid / 4);

    #pragma unroll 4
    for (int k = k0; k < k1; ++k) {
        float h = b1[k];
        #pragma unroll
        for (int d = 0; d < 12; ++d) h = fmaf(f[d], W1[d * kHid + k], h);
        h = fmaxf(h, 0.0f);
        #pragma unroll
        for (int o = 0; o < 8; ++o) acc[o] = fmaf(h, W2[k * 8 + o], acc[o]);
    }

    #pragma unroll
    for (int o = 0; o < 8; ++o) red[wave][o][lane] = acc[o];
    __syncthreads();

    if (wave == 0 && valid) {
        float a[8];
        #pragma unroll
        for (int o = 0; o < 8; ++o)
            a[o] = red[0][o][lane] + red[1][o][lane] +
                   red[2][o][lane] + red[3][o][lane] + b2[o];

        float ymin_diff = (f[2] - f[10]) * 10.0f;
        bool mask = (f[0] <= f[5]) && (f[1] >= f[4]) &&
                    (f[2] <= f[11]) && (f[3] >= f[10]);
        float inter = mask ? 5.0f : -5.0f;

        float* zr = z + (size_t)n * kZrow;
        reinterpret_cast<float4*>(zr)[0] = {a[0], a[1], a[2], a[3]};
        reinterpret_cast<float4*>(zr)[1] = {a[4], a[5], a[6], a[7]};
        reinterpret_cast<float4*>(zr)[2] = {ymin_diff, inter, 0.0f, 0.0f};
    }
}

// ---------------------------------------------------------------------------
// Kernel 2: bucketize incidences into 98 coarse buckets (SoA, rel embedded).
// ---------------------------------------------------------------------------
__global__ __launch_bounds__(256) void bucketize(
    const int* __restrict__ sx,
    const int* __restrict__ sy,
    const float* __restrict__ rel,
    int* __restrict__ gcur,
    unsigned* __restrict__ bkey,
    float2* __restrict__ brel)
{
    __shared__ int      cnt[128];
    __shared__ int      scn[128];
    __shared__ int      startArr[129];
    __shared__ int      c2[128];
    __shared__ int      gbase[128];
    __shared__ unsigned stage_k[kChunkEnt];
    __shared__ float2   stage_r[kChunkEnt];

    int tid  = threadIdx.x;
    int e0   = blockIdx.x * kChunkE;
    int ecnt = min(kChunkE, kE - e0);

    if (tid < 128) cnt[tid] = 0;
    __syncthreads();

    int ea[kChunkE / 256], eb[kChunkE / 256];
    int ne = 0;
    for (int i = tid; i < ecnt; i += 256) {
        int a = sx[e0 + i];
        int b = sy[e0 + i];
        ea[ne] = a; eb[ne] = b; ++ne;
        atomicAdd(&cnt[a >> kCBShift], 1);
        atomicAdd(&cnt[b >> kCBShift], 1);
    }
    __syncthreads();

    if (tid < 128) scn[tid] = cnt[tid];
    __syncthreads();
    for (int off = 1; off < 128; off <<= 1) {
        int v = 0;
        if (tid < 128 && tid >= off) v = scn[tid - off];
        __syncthreads();
        if (tid < 128) scn[tid] += v;
        __syncthreads();
    }
    if (tid < 128) startArr[tid] = scn[tid] - cnt[tid];
    if (tid == 127) startArr[128] = scn[127];
    __syncthreads();

    if (tid < 128) {
        int c = (tid < kCB) ? cnt[tid] : 0;
        gbase[tid] = (c > 0) ? atomicAdd(&gcur[tid], c) : 0;
        c2[tid] = startArr[tid];
    }
    __syncthreads();

    ne = 0;
    for (int i = tid; i < ecnt; i += 256) {
        int a = ea[ne], b = eb[ne]; ++ne;
        float2 r = reinterpret_cast<const float2*>(rel)[e0 + i];
        int sa = atomicAdd(&c2[a >> kCBShift], 1);
        stage_k[sa] = (unsigned)b | ((unsigned)(a & (kCBNodes - 1)) << 17);
        stage_r[sa] = r;
        int sb = atomicAdd(&c2[b >> kCBShift], 1);
        stage_k[sb] = (unsigned)a | ((unsigned)(b & (kCBNodes - 1)) << 17) | (1u << 27);
        stage_r[sb] = r;
    }
    __syncthreads();

    int total = 2 * ecnt;
    for (int j = tid; j < total; j += 256) {
        int lo = 0, hi = kCB;
        while (hi - lo > 1) {
            int mid = (lo + hi) >> 1;
            if (startArr[mid] <= j) lo = mid; else hi = mid;
        }
        int idx = gbase[lo] + (j - startArr[lo]);
        if (idx < kCBCap) {
            size_t dst = (size_t)lo * kCBCap + idx;
            bkey[dst] = stage_k[j];
            brel[dst] = stage_r[j];
        }
    }
}

// ---------------------------------------------------------------------------
// Kernel 3 (tier1): counting-sort one bucket -> CSR, ONE 16B scatter/entry.
// ---------------------------------------------------------------------------
__global__ __launch_bounds__(1024) void sort_bucket16(
    const int* __restrict__ gcur,
    const unsigned* __restrict__ bkey,
    const float2* __restrict__ brel,
    uint4* __restrict__ sdata,
    int* __restrict__ rowptr,
    int* __restrict__ rowcnt)
{
    __shared__ int cnt1024[kCBNodes];
    __shared__ int scanb[kCBNodes];
    __shared__ int cur[kCBNodes];

    int tid = threadIdx.x;
    int b   = blockIdx.x;
    int n   = min(gcur[b], kCBCap);
    const unsigned* bk = bkey + (size_t)b * kCBCap;
    const float2*   br = brel + (size_t)b * kCBCap;

    cnt1024[tid] = 0;
    __syncthreads();

    for (int j = tid; j < n; j += 1024)
        atomicAdd(&cnt1024[(bk[j] >> 17) & 1023u], 1);
    __syncthreads();

    scanb[tid] = cnt1024[tid];
    __syncthreads();
    for (int off = 1; off < kCBNodes; off <<= 1) {
        int v = (tid >= off) ? scanb[tid - off] : 0;
        __syncthreads();
        scanb[tid] += v;
        __syncthreads();
    }
    int excl = scanb[tid] - cnt1024[tid];
    cur[tid] = excl;

    int node = (b << kCBShift) + tid;
    if (node < kN) {
        rowptr[node] = b * kCBCap + excl;
        rowcnt[node] = cnt1024[tid];
    }
    __syncthreads();

    for (int j = tid; j < n; j += 1024) {
        unsigned k = bk[j];
        float2  r  = br[j];
        int ol = (int)((k >> 17) & 1023u);
        int pos = atomicAdd(&cur[ol], 1);
        sdata[(size_t)b * kCBCap + pos] =
            make_uint4(k, __float_as_uint(r.x), __float_as_uint(r.y), 0u);
    }
}

// ---------------------------------------------------------------------------
// Kernel 4 (tier1): gather layer from 16B entries, register accumulation.
// ---------------------------------------------------------------------------
__global__ __launch_bounds__(256) void gather16(
    const float* __restrict__ zin,
    float* __restrict__ zout,
    const uint4* __restrict__ sdata,
    const int* __restrict__ rowptr,
    const int* __restrict__ rowcnt,
    const float* __restrict__ cw,
    int layer)
{
    int node = blockIdx.x * 16 + (threadIdx.x >> 4);
    int lane = threadIdx.x & 15;
    if (node >= kN) return;

    float w  = cw[layer];
    float sw = fmaxf(w, 0.0f) + log1pf(__expf(-fabsf(w)));  // softplus

    const float* zs = zin + (size_t)node * kZrow;
    float4 s0 = reinterpret_cast<const float4*>(zs)[0];
    float4 s1 = reinterpret_cast<const float4*>(zs)[1];
    float4 s2 = reinterpret_cast<const float4*>(zs)[2];
    float self[10] = {s0.x, s0.y, s0.z, s0.w, s1.x, s1.y, s1.z, s1.w, s2.x, s2.y};

    float acc[10] = {0,0,0,0,0,0,0,0,0,0};
    int rp = rowptr[node];
    int rc = rowcnt[node];

    for (int i = lane; i < rc; i += 16) {
        uint4 ent = sdata[rp + i];
        unsigned k = ent.x;
        float rx = __uint_as_float(ent.y);
        float ry = __uint_as_float(ent.z);
        int p    = (int)(k & 0x1FFFFu);
        int side = (int)((k >> 27) & 1u);

        const float* zp = zin + (size_t)p * kZrow;
        float4 p0 = reinterpret_cast<const float4*>(zp)[0];
        float4 p1 = reinterpret_cast<const float4*>(zp)[1];
        float2 p2 = reinterpret_cast<const float2*>(zp + 8)[0];
        float part[10] = {p0.x, p0.y, p0.z, p0.w, p1.x, p1.y, p1.z, p1.w, p2.x, p2.y};

        float t[22];
        #pragma unroll
        for (int j = 0; j < 10; ++j) {
            float ga = side ? part[j] : self[j];
            float gb = side ? self[j] : part[j];
            t[j]      = (j & 1) ? -ga : ga;
            t[10 + j] = (j & 1) ? -gb : gb;
        }
        t[20] = rx;
        t[21] = -ry;

        float m = t[0];
        #pragma unroll
        for (int j = 1; j < 22; ++j) m = fmaxf(m, t[j]);

        float pe[22];
        float ssum = 0.0f;
        #pragma unroll
        for (int j = 0; j < 22; ++j) { pe[j] = __expf(t[j] - m); ssum += pe[j]; }

        float scale = sw / ssum;
        #pragma unroll
        for (int j = 0; j < 10; ++j) {
            float pv = side ? pe[10 + j] : pe[j];
            acc[j] += ((j & 1) ? -scale : scale) * pv;
        }
    }

    #pragma unroll
    for (int m16 = 8; m16 >= 1; m16 >>= 1) {
        #pragma unroll
        for (int j = 0; j < 10; ++j)
            acc[j] += __shfl_xor(acc[j], m16, 16);
    }

    if (lane == 0) {
        float* zo = zout + (size_t)node * kZrow;
        reinterpret_cast<float4*>(zo)[0] =
            {self[0] + acc[0], self[1] + acc[1], self[2] + acc[2], self[3] + acc[3]};
        reinterpret_cast<float4*>(zo)[1] =
            {self[4] + acc[4], self[5] + acc[5], self[6] + acc[6], self[7] + acc[7]};
        reinterpret_cast<float4*>(zo)[2] =
            {self[8] + acc[8], self[9] + acc[9], s2.z, s2.w};
    }
}

// ---------------------------------------------------------------------------
// Kernel 5 (tier1): final gather layer fused with output heads.
// ---------------------------------------------------------------------------
__global__ __launch_bounds__(256) void gather16_out(
    const float* __restrict__ zin,
    float* __restrict__ out,
    const uint4* __restrict__ sdata,
    const int* __restrict__ rowptr,
    const int* __restrict__ rowcnt,
    const float* __restrict__ cw,
    int layer)
{
    int node = blockIdx.x * 16 + (threadIdx.x >> 4);
    int lane = threadIdx.x & 15;
    if (node >= kN) return;

    float w  = cw[layer];
    float sw = fmaxf(w, 0.0f) + log1pf(__expf(-fabsf(w)));

    const float* zs = zin + (size_t)node * kZrow;
    float4 s0 = reinterpret_cast<const float4*>(zs)[0];
    float4 s1 = reinterpret_cast<const float4*>(zs)[1];
    float4 s2 = reinterpret_cast<const float4*>(zs)[2];
    float self[10] = {s0.x, s0.y, s0.z, s0.w, s1.x, s1.y, s1.z, s1.w, s2.x, s2.y};

    float acc[8] = {0,0,0,0,0,0,0,0};
    int rp = rowptr[node];
    int rc = rowcnt[node];

    for (int i = lane; i < rc; i += 16) {
        uint4 ent = sdata[rp + i];
        unsigned k = ent.x;
        float rx = __uint_as_float(ent.y);
        float ry = __uint_as_float(ent.z);
        int p    = (int)(k & 0x1FFFFu);
        int side = (int)((k >> 27) & 1u);

        const float* zp = zin + (size_t)p * kZrow;
        float4 p0 = reinterpret_cast<const float4*>(zp)[0];
        float4 p1 = reinterpret_cast<const float4*>(zp)[1];
        float2 p2 = reinterpret_cast<const float2*>(zp + 8)[0];
        float part[10] = {p0.x, p0.y, p0.z, p0.w, p1.x, p1.y, p1.z, p1.w, p2.x, p2.y};

        float t[22];
        #pragma unroll
        for (int j = 0; j < 10; ++j) {
            float ga = side ? part[j] : self[j];
            float gb = side ? self[j] : part[j];
            t[j]      = (j & 1) ? -ga : ga;
            t[10 + j] = (j & 1) ? -gb : gb;
        }
        t[20] = rx;
        t[21] = -ry;

        float m = t[0];
        #pragma unroll
        for (int j = 1; j < 22; ++j) m = fmaxf(m, t[j]);

        float pe[22];
        float ssum = 0.0f;
        #pragma unroll
        for (int j = 0; j < 22; ++j) { pe[j] = __expf(t[j] - m); ssum += pe[j]; }

        float scale = sw / ssum;
        #pragma unroll
        for (int j = 0; j < 8; ++j) {
            float pv = side ? pe[10 + j] : pe[j];
            acc[j] += ((j & 1) ? -scale : scale) * pv;
        }
    }

    #pragma unroll
    for (int m16 = 8; m16 >= 1; m16 >>= 1) {
        #pragma unroll
        for (int j = 0; j < 8; ++j)
            acc[j] += __shfl_xor(acc[j], m16, 16);
    }

    if (lane == 0) {
        float4 za = {self[0] + acc[0], self[1] + acc[1], self[2] + acc[2], self[3] + acc[3]};
        float4 zb = {self[4] + acc[4], self[5] + acc[5], self[6] + acc[6], self[7] + acc[7]};

        float ma = fmaxf(fmaxf(za.x, za.y), fmaxf(za.z, za.w));
        float ea0 = __expf(za.x - ma), ea1 = __expf(za.y - ma);
        float ea2 = __expf(za.z - ma), ea3 = __expf(za.w - ma);
        float ia = 1.0f / (ea0 + ea1 + ea2 + ea3);
        float4 sma = {ea0 * ia, ea1 * ia, ea2 * ia, ea3 * ia};

        float mb = fmaxf(fmaxf(zb.x, zb.y), fmaxf(zb.z, zb.w));
        float eb0 = __expf(zb.x - mb), eb1 = __expf(zb.y - mb);
        float eb2 = __expf(zb.z - mb), eb3 = __expf(zb.w - mb);
        float ib = 1.0f / (eb0 + eb1 + eb2 + eb3);
        float4 smb = {eb0 * ib, eb1 * ib, eb2 * ib, eb3 * ib};

        reinterpret_cast<float4*>(out)[node]           = za;
        reinterpret_cast<float4*>(out + 4 * kN)[node]  = sma;
        reinterpret_cast<float4*>(out + 8 * kN)[node]  = zb;
        reinterpret_cast<float4*>(out + 12 * kN)[node] = smb;
    }
}

// ---------------------------------------------------------------------------
// Tier2 (R6-proven): split-stream sort + gather + out.
// ---------------------------------------------------------------------------
__global__ __launch_bounds__(1024) void sort_bucket(
    const int* __restrict__ gcur,
    const unsigned* __restrict__ bkey,
    const float2* __restrict__ brel,
    unsigned* __restrict__ skey,
    float2* __restrict__ srel,
    int* __restrict__ rowptr,
    int* __restrict__ rowcnt)
{
    __shared__ int cnt1024[kCBNodes];
    __shared__ int scanb[kCBNodes];
    __shared__ int cur[kCBNodes];

    int tid = threadIdx.x;
    int b   = blockIdx.x;
    int n   = min(gcur[b], kCBCap);
    const unsigned* bk = bkey + (size_t)b * kCBCap;
    const float2*   br = brel + (size_t)b * kCBCap;

    cnt1024[tid] = 0;
    __syncthreads();
    for (int j = tid; j < n; j += 1024)
        atomicAdd(&cnt1024[(bk[j] >> 17) & 1023u], 1);
    __syncthreads();

    scanb[tid] = cnt1024[tid];
    __syncthreads();
    for (int off = 1; off < kCBNodes; off <<= 1) {
        int v = (tid >= off) ? scanb[tid - off] : 0;
        __syncthreads();
        scanb[tid] += v;
        __syncthreads();
    }
    int excl = scanb[tid] - cnt1024[tid];
    cur[tid] = excl;

    int node = (b << kCBShift) + tid;
    if (node < kN) {
        rowptr[node] = b * kCBCap + excl;
        rowcnt[node] = cnt1024[tid];
    }
    __syncthreads();

    for (int j = tid; j < n; j += 1024) {
        unsigned k = bk[j];
        float2  r  = br[j];
        int ol = (int)((k >> 17) & 1023u);
        int pos = atomicAdd(&cur[ol], 1);
        size_t dst = (size_t)b * kCBCap + pos;
        skey[dst] = k;
        srel[dst] = r;
    }
}

__global__ __launch_bounds__(256) void kenn_gather_csr(
    const float* __restrict__ zin,
    float* __restrict__ zout,
    const unsigned* __restrict__ skey,
    const float2* __restrict__ srel,
    const int* __restrict__ rowptr,
    const int* __restrict__ rowcnt,
    const float* __restrict__ cw,
    int layer)
{
    int node = blockIdx.x * 16 + (threadIdx.x >> 4);
    int lane = threadIdx.x & 15;
    if (node >= kN) return;

    float w  = cw[layer];
    float sw = fmaxf(w, 0.0f) + log1pf(__expf(-fabsf(w)));

    const float* zs = zin + (size_t)node * kZrow;
    float4 s0 = reinterpret_cast<const float4*>(zs)[0];
    float4 s1 = reinterpret_cast<const float4*>(zs)[1];
    float4 s2 = reinterpret_cast<const float4*>(zs)[2];
    float self[10] = {s0.x, s0.y, s0.z, s0.w, s1.x, s1.y, s1.z, s1.w, s2.x, s2.y};

    float acc[10] = {0,0,0,0,0,0,0,0,0,0};
    int rp = rowptr[node];
    int rc = rowcnt[node];

    for (int i = lane; i < rc; i += 16) {
        unsigned k = skey[rp + i];
        float2  r  = srel[rp + i];
        int p    = (int)(k & 0x1FFFFu);
        int side = (int)((k >> 27) & 1u);

        const float* zp = zin + (size_t)p * kZrow;
        float4 p0 = reinterpret_cast<const float4*>(zp)[0];
        float4 p1 = reinterpret_cast<const float4*>(zp)[1];
        float2 p2 = reinterpret_cast<const float2*>(zp + 8)[0];
        float part[10] = {p0.x, p0.y, p0.z, p0.w, p1.x, p1.y, p1.z, p1.w, p2.x, p2.y};

        float t[22];
        #pragma unroll
        for (int j = 0; j < 10; ++j) {
            float ga = side ? part[j] : self[j];
            float gb = side ? self[j] : part[j];
            t[j]      = (j & 1) ? -ga : ga;
            t[10 + j] = (j & 1) ? -gb : gb;
        }
        t[20] = r.x;
        t[21] = -r.y;

        float m = t[0];
        #pragma unroll
        for (int j = 1; j < 22; ++j) m = fmaxf(m, t[j]);

        float pe[22];
        float ssum = 0.0f;
        #pragma unroll
        for (int j = 0; j < 22; ++j) { pe[j] = __expf(t[j] - m); ssum += pe[j]; }

        float scale = sw / ssum;
        #pragma unroll
        for (int j = 0; j < 10; ++j) {
            float pv = side ? pe[10 + j] : pe[j];
            acc[j] += ((j & 1) ? -scale : scale) * pv;
        }
    }

    #pragma unroll
    for (int m16 = 8; m16 >= 1; m16 >>= 1) {
        #pragma unroll
        for (int j = 0; j < 10; ++j)
            acc[j] += __shfl_xor(acc[j], m16, 16);
    }

    if (lane == 0) {
        float* zo = zout + (size_t)node * kZrow;
        reinterpret_cast<float4*>(zo)[0] =
            {self[0] + acc[0], self[1] + acc[1], self[2] + acc[2], self[3] + acc[3]};
        reinterpret_cast<float4*>(zo)[1] =
            {self[4] + acc[4], self[5] + acc[5], self[6] + acc[6], self[7] + acc[7]};
        reinterpret_cast<float4*>(zo)[2] =
            {self[8] + acc[8], self[9] + acc[9], s2.z, s2.w};
    }
}

__global__ __launch_bounds__(256) void out_kernel(
    const float* __restrict__ z,
    float* __restrict__ out)
{
    int n = blockIdx.x * blockDim.x + threadIdx.x;
    if (n >= kN) return;

    const float* zr = z + (size_t)n * kZrow;
    float4 za = reinterpret_cast<const float4*>(zr)[0];
    float4 zb = reinterpret_cast<const float4*>(zr)[1];

    float ma = fmaxf(fmaxf(za.x, za.y), fmaxf(za.z, za.w));
    float ea0 = __expf(za.x - ma), ea1 = __expf(za.y - ma);
    float ea2 = __expf(za.z - ma), ea3 = __expf(za.w - ma);
    float ia = 1.0f / (ea0 + ea1 + ea2 + ea3);
    float4 sma = {ea0 * ia, ea1 * ia, ea2 * ia, ea3 * ia};

    float mb = fmaxf(fmaxf(zb.x, zb.y), fmaxf(zb.z, zb.w));
    float eb0 = __expf(zb.x - mb), eb1 = __expf(zb.y - mb);
    float eb2 = __expf(zb.z - mb), eb3 = __expf(zb.w - mb);
    float ib = 1.0f / (eb0 + eb1 + eb2 + eb3);
    float4 smb = {eb0 * ib, eb1 * ib, eb2 * ib, eb3 * ib};

    reinterpret_cast<float4*>(out)[n]           = za;
    reinterpret_cast<float4*>(out + 4 * kN)[n]  = sma;
    reinterpret_cast<float4*>(out + 8 * kN)[n]  = zb;
    reinterpret_cast<float4*>(out + 12 * kN)[n] = smb;
}

// ---------------------------------------------------------------------------
// Tier3 (R1-proven): atomic scatter, minimal ws.
// ---------------------------------------------------------------------------
__global__ __launch_bounds__(256) void edge_kernel(
    const float* __restrict__ zin,
    float* __restrict__ zout,
    const float* __restrict__ rel,
    const int* __restrict__ sx,
    const int* __restrict__ sy,
    const float* __restrict__ cw,
    int layer)
{
    int e = blockIdx.x * blockDim.x + threadIdx.x;
    if (e >= kE) return;

    float w  = cw[layer];
    float sw = fmaxf(w, 0.0f) + log1pf(__expf(-fabsf(w)));

    int a = sx[e];
    int b = sy[e];
    float2 r = reinterpret_cast<const float2*>(rel)[e];

    const float* za = zin + (size_t)a * kZrow;
    const float* zb = zin + (size_t)b * kZrow;
    float4 a0 = reinterpret_cast<const float4*>(za)[0];
    float4 a1 = reinterpret_cast<const float4*>(za)[1];
    float2 a2 = reinterpret_cast<const float2*>(za + 8)[0];
    float4 b0 = reinterpret_cast<const float4*>(zb)[0];
    float4 b1v = reinterpret_cast<const float4*>(zb)[1];
    float2 b2v = reinterpret_cast<const float2*>(zb + 8)[0];

    float t[22];
    t[0]  =  a0.x;  t[1]  = -a0.y;  t[2]  =  a0.z;  t[3]  = -a0.w;
    t[4]  =  a1.x;  t[5]  = -a1.y;  t[6]  =  a1.z;  t[7]  = -a1.w;
    t[8]  =  a2.x;  t[9]  = -a2.y;
    t[10] =  b0.x;  t[11] = -b0.y;  t[12] =  b0.z;  t[13] = -b0.w;
    t[14] =  b1v.x; t[15] = -b1v.y; t[16] =  b1v.z; t[17] = -b1v.w;
    t[18] =  b2v.x; t[19] = -b2v.y;
    t[20] =  r.x;   t[21] = -r.y;

    float m = t[0];
    #pragma unroll
    for (int i = 1; i < 22; ++i) m = fmaxf(m, t[i]);
    float p[22]; float s = 0.0f;
    #pragma unroll
    for (int i = 0; i < 22; ++i) { p[i] = __expf(t[i] - m); s += p[i]; }
    float scale = sw / s;

    float* oa = zout + (size_t)a * kZrow;
    float* ob = zout + (size_t)b * kZrow;
    #pragma unroll
    for (int i = 0; i < 10; ++i)
        unsafeAtomicAdd(oa + i, ((i & 1) ? -scale : scale) * p[i]);
    #pragma unroll
    for (int i = 0; i < 10; ++i)
        unsafeAtomicAdd(ob + i, ((i & 1) ? -scale : scale) * p[10 + i]);
}

// ---------------------------------------------------------------------------
extern "C" void kernel_launch(void* const* d_in, const int* in_sizes, int n_in,
                              void* d_out, int out_size, void* d_ws, size_t ws_size,
                              hipStream_t stream)
{
    const float* feat = (const float*)d_in[0];
    const float* rel  = (const float*)d_in[1];
    const float* W1   = (const float*)d_in[2];
    const float* b1   = (const float*)d_in[3];
    const float* W2   = (const float*)d_in[4];
    const float* b2   = (const float*)d_in[5];
    const float* cw   = (const float*)d_in[6];
    const int*   sx   = (const int*)d_in[7];
    const int*   sy   = (const int*)d_in[8];
    float* out = (float*)d_out;

    // ws layout (bytes)
    char* ws = (char*)d_ws;
    const size_t off_zA     = 0;                        // 4,800,000
    const size_t off_zB     = 4800000;                  // 4,800,000
    const size_t off_gcur   = 9600000;                  // 512
    const size_t off_rowptr = 9600512;                  // 400,384
    const size_t off_rowcnt = 10000896;                 // 400,384
    const size_t off_bkey   = 10401280;                 // 98*68000*4  = 26,656,000
    const size_t off_brel   = 37057280;                 // 98*68000*8  = 53,312,000
    const size_t off_sdata  = 90369280;                 // 98*68000*16 = 106,624,000
    const size_t need_t1    = 196993280;                // ~197 MB
    const size_t off_skey   = off_sdata;                // tier2: 26,656,000
    const size_t off_srel   = 117025280;                // tier2: 53,312,000
    const size_t need_t2    = 170337280;                // ~170 MB (proven <= ws)

    float*    zA     = (float*)(ws + off_zA);
    float*    zB     = (float*)(ws + off_zB);
    int*      gcur   = (int*)(ws + off_gcur);
    int*      rowptr = (int*)(ws + off_rowptr);
    int*      rowcnt = (int*)(ws + off_rowcnt);
    unsigned* bkey   = (unsigned*)(ws + off_bkey);
    float2*   brel   = (float2*)(ws + off_brel);
    uint4*    sdata  = (uint4*)(ws + off_sdata);
    unsigned* skey   = (unsigned*)(ws + off_skey);
    float2*   srel   = (float2*)(ws + off_srel);

    dim3 blk(256);
    dim3 gN((kN + 255) / 256);
    dim3 gE((kE + 255) / 256);
    dim3 gB((kE + kChunkE - 1) / kChunkE);
    dim3 gG(kN / 16);                       // 6250
    dim3 gM((kN + 63) / 64);                // 1563 blocks, 4 waves each

    mlp_kernel4<<<gM, blk, 0, stream>>>(feat, W1, b1, W2, b2, zA);

    if (ws_size >= need_t1) {
        hipMemsetAsync(gcur, 0, 512, stream);
        bucketize<<<gB, blk, 0, stream>>>(sx, sy, rel, gcur, bkey, brel);
        sort_bucket16<<<dim3(kCB), dim3(1024), 0, stream>>>(gcur, bkey, brel,
                                                            sdata, rowptr, rowcnt);
        gather16<<<gG, blk, 0, stream>>>(zA, zB, sdata, rowptr, rowcnt, cw, 0);
        gather16<<<gG, blk, 0, stream>>>(zB, zA, sdata, rowptr, rowcnt, cw, 1);
        gather16_out<<<gG, blk, 0, stream>>>(zA, out, sdata, rowptr, rowcnt, cw, 2);
    } else if (ws_size >= need_t2) {
        hipMemsetAsync(gcur, 0, 512, stream);
        bucketize<<<gB, blk, 0, stream>>>(sx, sy, rel, gcur, bkey, brel);
        sort_bucket<<<dim3(kCB), dim3(1024), 0, stream>>>(gcur, bkey, brel,
                                                          skey, srel, rowptr, rowcnt);
        kenn_gather_csr<<<gG, blk, 0, stream>>>(zA, zB, skey, srel, rowptr, rowcnt, cw, 0);
        kenn_gather_csr<<<gG, blk, 0, stream>>>(zB, zA, skey, srel, rowptr, rowcnt, cw, 1);
        kenn_gather_csr<<<gG, blk, 0, stream>>>(zA, zB, skey, srel, rowptr, rowcnt, cw, 2);
        out_kernel<<<gN, blk, 0, stream>>>(zB, out);
    } else {
        size_t zbytes = (size_t)kN * kZrow * sizeof(float);
        hipMemcpyAsync(zB, zA, zbytes, hipMemcpyDeviceToDevice, stream);
        edge_kernel<<<gE, blk, 0, stream>>>(zA, zB, rel, sx, sy, cw, 0);
        hipMemcpyAsync(zA, zB, zbytes, hipMemcpyDeviceToDevice, stream);
        edge_kernel<<<gE, blk, 0, stream>>>(zB, zA, rel, sx, sy, cw, 1);
        hipMemcpyAsync(zB, zA, zbytes, hipMemcpyDeviceToDevice, stream);
        edge_kernel<<<gE, blk, 0, stream>>>(zA, zB, rel, sx, sy, cw, 2);
        out_kernel<<<gN, blk, 0, stream>>>(zB, out);
    }
}

// Round 10
// 559.586 us; speedup vs baseline: 2.8182x; 1.0561x over previous
//
#include <hip/hip_runtime.h>
#include <math.h>

constexpr int kN    = 100000;
constexpr int kE    = 3200000;
constexpr int kHid  = 1024;
constexpr int kZrow = 12;

// coarse buckets: 1024 nodes each
constexpr int kCBShift = 10;
constexpr int kCBNodes = 1 << kCBShift;                    // 1024
constexpr int kCB      = (kN + kCBNodes - 1) / kCBNodes;   // 98
constexpr int kCBCap   = 66800;                            // mean 65536, +5 sigma
constexpr int kSeg     = 8;                                // scatter segments/bucket
constexpr int kChunkE  = 1024;                             // edges per bucketize block
constexpr int kChunkEnt= kChunkE * 2;

// key layout: partner[16:0] | own_local[26:17] | side[27]

// ---------------------------------------------------------------------------
// Kernel 1: per-node MLP + derived columns. 4 waves split the 1024 hidden
// units of 64 nodes; LDS reduce (R9: 182 -> ~50 us, occupancy fix).
// ---------------------------------------------------------------------------
__global__ __launch_bounds__(256) void mlp_kernel4(
    const float* __restrict__ feat,
    const float* __restrict__ W1,
    const float* __restrict__ b1,
    const float* __restrict__ W2,
    const float* __restrict__ b2,
    float* __restrict__ z)
{
    __shared__ float red[4][8][64];          // [wave][out][node-lane], 8 KB

    int wave = (int)__builtin_amdgcn_readfirstlane(threadIdx.x >> 6);
    int lane = threadIdx.x & 63;
    int n    = blockIdx.x * 64 + lane;
    bool valid = n < kN;
    int nc   = valid ? n : (kN - 1);

    const float4* fr = reinterpret_cast<const float4*>(feat + (size_t)nc * 12);
    float4 f0 = fr[0], f1 = fr[1], f2 = fr[2];
    float f[12] = {f0.x, f0.y, f0.z, f0.w,
                   f1.x, f1.y, f1.z, f1.w,
                   f2.x, f2.y, f2.z, f2.w};

    float acc[8] = {0,0,0,0,0,0,0,0};
    int k0 = wave * (kHid / 4);
    int k1 = k0 + (kHid / 4);

    #pragma unroll 4
    for (int k = k0; k < k1; ++k) {
        float h = b1[k];
        #pragma unroll
        for (int d = 0; d < 12; ++d) h = fmaf(f[d], W1[d * kHid + k], h);
        h = fmaxf(h, 0.0f);
        #pragma unroll
        for (int o = 0; o < 8; ++o) acc[o] = fmaf(h, W2[k * 8 + o], acc[o]);
    }

    #pragma unroll
    for (int o = 0; o < 8; ++o) red[wave][o][lane] = acc[o];
    __syncthreads();

    if (wave == 0 && valid) {
        float a[8];
        #pragma unroll
        for (int o = 0; o < 8; ++o)
            a[o] = red[0][o][lane] + red[1][o][lane] +
                   red[2][o][lane] + red[3][o][lane] + b2[o];

        float ymin_diff = (f[2] - f[10]) * 10.0f;
        bool mask = (f[0] <= f[5]) && (f[1] >= f[4]) &&
                    (f[2] <= f[11]) && (f[3] >= f[10]);
        float inter = mask ? 5.0f : -5.0f;

        float* zr = z + (size_t)n * kZrow;
        reinterpret_cast<float4*>(zr)[0] = {a[0], a[1], a[2], a[3]};
        reinterpret_cast<float4*>(zr)[1] = {a[4], a[5], a[6], a[7]};
        reinterpret_cast<float4*>(zr)[2] = {ymin_diff, inter, 0.0f, 0.0f};
    }
}

// ---------------------------------------------------------------------------
// Kernel 2: bucketize incidences into 98 coarse buckets (SoA, rel embedded).
// ---------------------------------------------------------------------------
__global__ __launch_bounds__(256) void bucketize(
    const int* __restrict__ sx,
    const int* __restrict__ sy,
    const float* __restrict__ rel,
    int* __restrict__ gcur,
    unsigned* __restrict__ bkey,
    float2* __restrict__ brel)
{
    __shared__ int      cnt[128];
    __shared__ int      scn[128];
    __shared__ int      startArr[129];
    __shared__ int      c2[128];
    __shared__ int      gbase[128];
    __shared__ unsigned stage_k[kChunkEnt];
    __shared__ float2   stage_r[kChunkEnt];

    int tid  = threadIdx.x;
    int e0   = blockIdx.x * kChunkE;
    int ecnt = min(kChunkE, kE - e0);

    if (tid < 128) cnt[tid] = 0;
    __syncthreads();

    int ea[kChunkE / 256], eb[kChunkE / 256];
    int ne = 0;
    for (int i = tid; i < ecnt; i += 256) {
        int a = sx[e0 + i];
        int b = sy[e0 + i];
        ea[ne] = a; eb[ne] = b; ++ne;
        atomicAdd(&cnt[a >> kCBShift], 1);
        atomicAdd(&cnt[b >> kCBShift], 1);
    }
    __syncthreads();

    if (tid < 128) scn[tid] = cnt[tid];
    __syncthreads();
    for (int off = 1; off < 128; off <<= 1) {
        int v = 0;
        if (tid < 128 && tid >= off) v = scn[tid - off];
        __syncthreads();
        if (tid < 128) scn[tid] += v;
        __syncthreads();
    }
    if (tid < 128) startArr[tid] = scn[tid] - cnt[tid];
    if (tid == 127) startArr[128] = scn[127];
    __syncthreads();

    if (tid < 128) {
        int c = (tid < kCB) ? cnt[tid] : 0;
        gbase[tid] = (c > 0) ? atomicAdd(&gcur[tid], c) : 0;
        c2[tid] = startArr[tid];
    }
    __syncthreads();

    ne = 0;
    for (int i = tid; i < ecnt; i += 256) {
        int a = ea[ne], b = eb[ne]; ++ne;
        float2 r = reinterpret_cast<const float2*>(rel)[e0 + i];
        int sa = atomicAdd(&c2[a >> kCBShift], 1);
        stage_k[sa] = (unsigned)b | ((unsigned)(a & (kCBNodes - 1)) << 17);
        stage_r[sa] = r;
        int sb = atomicAdd(&c2[b >> kCBShift], 1);
        stage_k[sb] = (unsigned)a | ((unsigned)(b & (kCBNodes - 1)) << 17) | (1u << 27);
        stage_r[sb] = r;
    }
    __syncthreads();

    int total = 2 * ecnt;
    for (int j = tid; j < total; j += 256) {
        int lo = 0, hi = kCB;
        while (hi - lo > 1) {
            int mid = (lo + hi) >> 1;
            if (startArr[mid] <= j) lo = mid; else hi = mid;
        }
        int idx = gbase[lo] + (j - startArr[lo]);
        if (idx < kCBCap) {
            size_t dst = (size_t)lo * kCBCap + idx;
            bkey[dst] = stage_k[j];
            brel[dst] = stage_r[j];
        }
    }
}

// ---------------------------------------------------------------------------
// Sort phase A: per-(bucket,segment) node histogram. 784 blocks.
// ---------------------------------------------------------------------------
__global__ __launch_bounds__(1024) void seg_hist(
    const int* __restrict__ gcur,
    const unsigned* __restrict__ bkey,
    int* __restrict__ seghist)
{
    __shared__ int hist[kCBNodes];

    int tid = threadIdx.x;
    int b   = blockIdx.x / kSeg;
    int s   = blockIdx.x % kSeg;
    int n   = min(gcur[b], kCBCap);
    int j0  = (int)((long long)n * s / kSeg);
    int j1  = (int)((long long)n * (s + 1) / kSeg);
    const unsigned* bk = bkey + (size_t)b * kCBCap;

    hist[tid] = 0;
    __syncthreads();

    for (int j = j0 + tid; j < j1; j += 1024)
        atomicAdd(&hist[(bk[j] >> 17) & 1023u], 1);
    __syncthreads();

    seghist[(size_t)blockIdx.x * kCBNodes + tid] = hist[tid];
}

// ---------------------------------------------------------------------------
// Sort phase B: per bucket, rowcnt/rowptr + per-segment base cursors. 98 blocks.
// ---------------------------------------------------------------------------
__global__ __launch_bounds__(1024) void seg_base(
    int* __restrict__ seghist,     // in: counts, out: base cursors (in-place)
    int* __restrict__ rowptr,
    int* __restrict__ rowcnt)
{
    __shared__ int scanb[kCBNodes];

    int tid = threadIdx.x;
    int b   = blockIdx.x;

    int c[kSeg];
    int tot = 0;
    #pragma unroll
    for (int s = 0; s < kSeg; ++s) {
        c[s] = seghist[((size_t)(b * kSeg + s)) * kCBNodes + tid];
        tot += c[s];
    }

    scanb[tid] = tot;
    __syncthreads();
    for (int off = 1; off < kCBNodes; off <<= 1) {
        int v = (tid >= off) ? scanb[tid - off] : 0;
        __syncthreads();
        scanb[tid] += v;
        __syncthreads();
    }
    int excl = scanb[tid] - tot;

    int node = (b << kCBShift) + tid;
    if (node < kN) {
        rowptr[node] = b * kCBCap + excl;
        rowcnt[node] = tot;
    }

    int base = excl;
    #pragma unroll
    for (int s = 0; s < kSeg; ++s) {
        seghist[((size_t)(b * kSeg + s)) * kCBNodes + tid] = base;
        base += c[s];
    }
}

// ---------------------------------------------------------------------------
// Sort phase C: segmented scatter with LDS cursors. 784 blocks -> all CUs.
// ---------------------------------------------------------------------------
__global__ __launch_bounds__(1024) void seg_scatter(
    const int* __restrict__ gcur,
    const unsigned* __restrict__ bkey,
    const float2* __restrict__ brel,
    const int* __restrict__ seghist,
    uint4* __restrict__ sdata)
{
    __shared__ int cur[kCBNodes];

    int tid = threadIdx.x;
    int b   = blockIdx.x / kSeg;
    int s   = blockIdx.x % kSeg;
    int n   = min(gcur[b], kCBCap);
    int j0  = (int)((long long)n * s / kSeg);
    int j1  = (int)((long long)n * (s + 1) / kSeg);
    const unsigned* bk = bkey + (size_t)b * kCBCap;
    const float2*   br = brel + (size_t)b * kCBCap;

    cur[tid] = seghist[(size_t)blockIdx.x * kCBNodes + tid];
    __syncthreads();

    for (int j = j0 + tid; j < j1; j += 1024) {
        unsigned k = bk[j];
        float2  r  = br[j];
        int ol = (int)((k >> 17) & 1023u);
        int pos = atomicAdd(&cur[ol], 1);
        sdata[(size_t)b * kCBCap + pos] =
            make_uint4(k, __float_as_uint(r.x), __float_as_uint(r.y), 0u);
    }
}

// ---------------------------------------------------------------------------
// Kernel 4 (tier1): gather layer from 16B entries, register accumulation.
// ---------------------------------------------------------------------------
__global__ __launch_bounds__(256) void gather16(
    const float* __restrict__ zin,
    float* __restrict__ zout,
    const uint4* __restrict__ sdata,
    const int* __restrict__ rowptr,
    const int* __restrict__ rowcnt,
    const float* __restrict__ cw,
    int layer)
{
    int node = blockIdx.x * 16 + (threadIdx.x >> 4);
    int lane = threadIdx.x & 15;
    if (node >= kN) return;

    float w  = cw[layer];
    float sw = fmaxf(w, 0.0f) + log1pf(__expf(-fabsf(w)));  // softplus

    const float* zs = zin + (size_t)node * kZrow;
    float4 s0 = reinterpret_cast<const float4*>(zs)[0];
    float4 s1 = reinterpret_cast<const float4*>(zs)[1];
    float4 s2 = reinterpret_cast<const float4*>(zs)[2];
    float self[10] = {s0.x, s0.y, s0.z, s0.w, s1.x, s1.y, s1.z, s1.w, s2.x, s2.y};

    float acc[10] = {0,0,0,0,0,0,0,0,0,0};
    int rp = rowptr[node];
    int rc = rowcnt[node];

    for (int i = lane; i < rc; i += 16) {
        uint4 ent = sdata[rp + i];
        unsigned k = ent.x;
        float rx = __uint_as_float(ent.y);
        float ry = __uint_as_float(ent.z);
        int p    = (int)(k & 0x1FFFFu);
        int side = (int)((k >> 27) & 1u);

        const float* zp = zin + (size_t)p * kZrow;
        float4 p0 = reinterpret_cast<const float4*>(zp)[0];
        float4 p1 = reinterpret_cast<const float4*>(zp)[1];
        float2 p2 = reinterpret_cast<const float2*>(zp + 8)[0];
        float part[10] = {p0.x, p0.y, p0.z, p0.w, p1.x, p1.y, p1.z, p1.w, p2.x, p2.y};

        float t[22];
        #pragma unroll
        for (int j = 0; j < 10; ++j) {
            float ga = side ? part[j] : self[j];
            float gb = side ? self[j] : part[j];
            t[j]      = (j & 1) ? -ga : ga;
            t[10 + j] = (j & 1) ? -gb : gb;
        }
        t[20] = rx;
        t[21] = -ry;

        float m = t[0];
        #pragma unroll
        for (int j = 1; j < 22; ++j) m = fmaxf(m, t[j]);

        float pe[22];
        float ssum = 0.0f;
        #pragma unroll
        for (int j = 0; j < 22; ++j) { pe[j] = __expf(t[j] - m); ssum += pe[j]; }

        float scale = sw / ssum;
        #pragma unroll
        for (int j = 0; j < 10; ++j) {
            float pv = side ? pe[10 + j] : pe[j];
            acc[j] += ((j & 1) ? -scale : scale) * pv;
        }
    }

    #pragma unroll
    for (int m16 = 8; m16 >= 1; m16 >>= 1) {
        #pragma unroll
        for (int j = 0; j < 10; ++j)
            acc[j] += __shfl_xor(acc[j], m16, 16);
    }

    if (lane == 0) {
        float* zo = zout + (size_t)node * kZrow;
        reinterpret_cast<float4*>(zo)[0] =
            {self[0] + acc[0], self[1] + acc[1], self[2] + acc[2], self[3] + acc[3]};
        reinterpret_cast<float4*>(zo)[1] =
            {self[4] + acc[4], self[5] + acc[5], self[6] + acc[6], self[7] + acc[7]};
        reinterpret_cast<float4*>(zo)[2] =
            {self[8] + acc[8], self[9] + acc[9], s2.z, s2.w};
    }
}

// ---------------------------------------------------------------------------
// Kernel 5 (tier1): final gather layer fused with output heads.
// ---------------------------------------------------------------------------
__global__ __launch_bounds__(256) void gather16_out(
    const float* __restrict__ zin,
    float* __restrict__ out,
    const uint4* __restrict__ sdata,
    const int* __restrict__ rowptr,
    const int* __restrict__ rowcnt,
    const float* __restrict__ cw,
    int layer)
{
    int node = blockIdx.x * 16 + (threadIdx.x >> 4);
    int lane = threadIdx.x & 15;
    if (node >= kN) return;

    float w  = cw[layer];
    float sw = fmaxf(w, 0.0f) + log1pf(__expf(-fabsf(w)));

    const float* zs = zin + (size_t)node * kZrow;
    float4 s0 = reinterpret_cast<const float4*>(zs)[0];
    float4 s1 = reinterpret_cast<const float4*>(zs)[1];
    float4 s2 = reinterpret_cast<const float4*>(zs)[2];
    float self[10] = {s0.x, s0.y, s0.z, s0.w, s1.x, s1.y, s1.z, s1.w, s2.x, s2.y};

    float acc[8] = {0,0,0,0,0,0,0,0};
    int rp = rowptr[node];
    int rc = rowcnt[node];

    for (int i = lane; i < rc; i += 16) {
        uint4 ent = sdata[rp + i];
        unsigned k = ent.x;
        float rx = __uint_as_float(ent.y);
        float ry = __uint_as_float(ent.z);
        int p    = (int)(k & 0x1FFFFu);
        int side = (int)((k >> 27) & 1u);

        const float* zp = zin + (size_t)p * kZrow;
        float4 p0 = reinterpret_cast<const float4*>(zp)[0];
        float4 p1 = reinterpret_cast<const float4*>(zp)[1];
        float2 p2 = reinterpret_cast<const float2*>(zp + 8)[0];
        float part[10] = {p0.x, p0.y, p0.z, p0.w, p1.x, p1.y, p1.z, p1.w, p2.x, p2.y};

        float t[22];
        #pragma unroll
        for (int j = 0; j < 10; ++j) {
            float ga = side ? part[j] : self[j];
            float gb = side ? self[j] : part[j];
            t[j]      = (j & 1) ? -ga : ga;
            t[10 + j] = (j & 1) ? -gb : gb;
        }
        t[20] = rx;
        t[21] = -ry;

        float m = t[0];
        #pragma unroll
        for (int j = 1; j < 22; ++j) m = fmaxf(m, t[j]);

        float pe[22];
        float ssum = 0.0f;
        #pragma unroll
        for (int j = 0; j < 22; ++j) { pe[j] = __expf(t[j] - m); ssum += pe[j]; }

        float scale = sw / ssum;
        #pragma unroll
        for (int j = 0; j < 8; ++j) {
            float pv = side ? pe[10 + j] : pe[j];
            acc[j] += ((j & 1) ? -scale : scale) * pv;
        }
    }

    #pragma unroll
    for (int m16 = 8; m16 >= 1; m16 >>= 1) {
        #pragma unroll
        for (int j = 0; j < 8; ++j)
            acc[j] += __shfl_xor(acc[j], m16, 16);
    }

    if (lane == 0) {
        float4 za = {self[0] + acc[0], self[1] + acc[1], self[2] + acc[2], self[3] + acc[3]};
        float4 zb = {self[4] + acc[4], self[5] + acc[5], self[6] + acc[6], self[7] + acc[7]};

        float ma = fmaxf(fmaxf(za.x, za.y), fmaxf(za.z, za.w));
        float ea0 = __expf(za.x - ma), ea1 = __expf(za.y - ma);
        float ea2 = __expf(za.z - ma), ea3 = __expf(za.w - ma);
        float ia = 1.0f / (ea0 + ea1 + ea2 + ea3);
        float4 sma = {ea0 * ia, ea1 * ia, ea2 * ia, ea3 * ia};

        float mb = fmaxf(fmaxf(zb.x, zb.y), fmaxf(zb.z, zb.w));
        float eb0 = __expf(zb.x - mb), eb1 = __expf(zb.y - mb);
        float eb2 = __expf(zb.z - mb), eb3 = __expf(zb.w - mb);
        float ib = 1.0f / (eb0 + eb1 + eb2 + eb3);
        float4 smb = {eb0 * ib, eb1 * ib, eb2 * ib, eb3 * ib};

        reinterpret_cast<float4*>(out)[node]           = za;
        reinterpret_cast<float4*>(out + 4 * kN)[node]  = sma;
        reinterpret_cast<float4*>(out + 8 * kN)[node]  = zb;
        reinterpret_cast<float4*>(out + 12 * kN)[node] = smb;
    }
}

// ---------------------------------------------------------------------------
// Tier2 (R6-proven): single-block-per-bucket sort + gather + out.
// ---------------------------------------------------------------------------
__global__ __launch_bounds__(1024) void sort_bucket(
    const int* __restrict__ gcur,
    const unsigned* __restrict__ bkey,
    const float2* __restrict__ brel,
    unsigned* __restrict__ skey,
    float2* __restrict__ srel,
    int* __restrict__ rowptr,
    int* __restrict__ rowcnt)
{
    __shared__ int cnt1024[kCBNodes];
    __shared__ int scanb[kCBNodes];
    __shared__ int cur[kCBNodes];

    int tid = threadIdx.x;
    int b   = blockIdx.x;
    int n   = min(gcur[b], kCBCap);
    const unsigned* bk = bkey + (size_t)b * kCBCap;
    const float2*   br = brel + (size_t)b * kCBCap;

    cnt1024[tid] = 0;
    __syncthreads();
    for (int j = tid; j < n; j += 1024)
        atomicAdd(&cnt1024[(bk[j] >> 17) & 1023u], 1);
    __syncthreads();

    scanb[tid] = cnt1024[tid];
    __syncthreads();
    for (int off = 1; off < kCBNodes; off <<= 1) {
        int v = (tid >= off) ? scanb[tid - off] : 0;
        __syncthreads();
        scanb[tid] += v;
        __syncthreads();
    }
    int excl = scanb[tid] - cnt1024[tid];
    cur[tid] = excl;

    int node = (b << kCBShift) + tid;
    if (node < kN) {
        rowptr[node] = b * kCBCap + excl;
        rowcnt[node] = cnt1024[tid];
    }
    __syncthreads();

    for (int j = tid; j < n; j += 1024) {
        unsigned k = bk[j];
        float2  r  = br[j];
        int ol = (int)((k >> 17) & 1023u);
        int pos = atomicAdd(&cur[ol], 1);
        size_t dst = (size_t)b * kCBCap + pos;
        skey[dst] = k;
        srel[dst] = r;
    }
}

__global__ __launch_bounds__(256) void kenn_gather_csr(
    const float* __restrict__ zin,
    float* __restrict__ zout,
    const unsigned* __restrict__ skey,
    const float2* __restrict__ srel,
    const int* __restrict__ rowptr,
    const int* __restrict__ rowcnt,
    const float* __restrict__ cw,
    int layer)
{
    int node = blockIdx.x * 16 + (threadIdx.x >> 4);
    int lane = threadIdx.x & 15;
    if (node >= kN) return;

    float w  = cw[layer];
    float sw = fmaxf(w, 0.0f) + log1pf(__expf(-fabsf(w)));

    const float* zs = zin + (size_t)node * kZrow;
    float4 s0 = reinterpret_cast<const float4*>(zs)[0];
    float4 s1 = reinterpret_cast<const float4*>(zs)[1];
    float4 s2 = reinterpret_cast<const float4*>(zs)[2];
    float self[10] = {s0.x, s0.y, s0.z, s0.w, s1.x, s1.y, s1.z, s1.w, s2.x, s2.y};

    float acc[10] = {0,0,0,0,0,0,0,0,0,0};
    int rp = rowptr[node];
    int rc = rowcnt[node];

    for (int i = lane; i < rc; i += 16) {
        unsigned k = skey[rp + i];
        float2  r  = srel[rp + i];
        int p    = (int)(k & 0x1FFFFu);
        int side = (int)((k >> 27) & 1u);

        const float* zp = zin + (size_t)p * kZrow;
        float4 p0 = reinterpret_cast<const float4*>(zp)[0];
        float4 p1 = reinterpret_cast<const float4*>(zp)[1];
        float2 p2 = reinterpret_cast<const float2*>(zp + 8)[0];
        float part[10] = {p0.x, p0.y, p0.z, p0.w, p1.x, p1.y, p1.z, p1.w, p2.x, p2.y};

        float t[22];
        #pragma unroll
        for (int j = 0; j < 10; ++j) {
            float ga = side ? part[j] : self[j];
            float gb = side ? self[j] : part[j];
            t[j]      = (j & 1) ? -ga : ga;
            t[10 + j] = (j & 1) ? -gb : gb;
        }
        t[20] = r.x;
        t[21] = -r.y;

        float m = t[0];
        #pragma unroll
        for (int j = 1; j < 22; ++j) m = fmaxf(m, t[j]);

        float pe[22];
        float ssum = 0.0f;
        #pragma unroll
        for (int j = 0; j < 22; ++j) { pe[j] = __expf(t[j] - m); ssum += pe[j]; }

        float scale = sw / ssum;
        #pragma unroll
        for (int j = 0; j < 10; ++j) {
            float pv = side ? pe[10 + j] : pe[j];
            acc[j] += ((j & 1) ? -scale : scale) * pv;
        }
    }

    #pragma unroll
    for (int m16 = 8; m16 >= 1; m16 >>= 1) {
        #pragma unroll
        for (int j = 0; j < 10; ++j)
            acc[j] += __shfl_xor(acc[j], m16, 16);
    }

    if (lane == 0) {
        float* zo = zout + (size_t)node * kZrow;
        reinterpret_cast<float4*>(zo)[0] =
            {self[0] + acc[0], self[1] + acc[1], self[2] + acc[2], self[3] + acc[3]};
        reinterpret_cast<float4*>(zo)[1] =
            {self[4] + acc[4], self[5] + acc[5], self[6] + acc[6], self[7] + acc[7]};
        reinterpret_cast<float4*>(zo)[2] =
            {self[8] + acc[8], self[9] + acc[9], s2.z, s2.w};
    }
}

__global__ __launch_bounds__(256) void out_kernel(
    const float* __restrict__ z,
    float* __restrict__ out)
{
    int n = blockIdx.x * blockDim.x + threadIdx.x;
    if (n >= kN) return;

    const float* zr = z + (size_t)n * kZrow;
    float4 za = reinterpret_cast<const float4*>(zr)[0];
    float4 zb = reinterpret_cast<const float4*>(zr)[1];

    float ma = fmaxf(fmaxf(za.x, za.y), fmaxf(za.z, za.w));
    float ea0 = __expf(za.x - ma), ea1 = __expf(za.y - ma);
    float ea2 = __expf(za.z - ma), ea3 = __expf(za.w - ma);
    float ia = 1.0f / (ea0 + ea1 + ea2 + ea3);
    float4 sma = {ea0 * ia, ea1 * ia, ea2 * ia, ea3 * ia};

    float mb = fmaxf(fmaxf(zb.x, zb.y), fmaxf(zb.z, zb.w));
    float eb0 = __expf(zb.x - mb), eb1 = __expf(zb.y - mb);
    float eb2 = __expf(zb.z - mb), eb3 = __expf(zb.w - mb);
    float ib = 1.0f / (eb0 + eb1 + eb2 + eb3);
    float4 smb = {eb0 * ib, eb1 * ib, eb2 * ib, eb3 * ib};

    reinterpret_cast<float4*>(out)[n]           = za;
    reinterpret_cast<float4*>(out + 4 * kN)[n]  = sma;
    reinterpret_cast<float4*>(out + 8 * kN)[n]  = zb;
    reinterpret_cast<float4*>(out + 12 * kN)[n] = smb;
}

// ---------------------------------------------------------------------------
// Tier3 (R1-proven): atomic scatter, minimal ws.
// ---------------------------------------------------------------------------
__global__ __launch_bounds__(256) void edge_kernel(
    const float* __restrict__ zin,
    float* __restrict__ zout,
    const float* __restrict__ rel,
    const int* __restrict__ sx,
    const int* __restrict__ sy,
    const float* __restrict__ cw,
    int layer)
{
    int e = blockIdx.x * blockDim.x + threadIdx.x;
    if (e >= kE) return;

    float w  = cw[layer];
    float sw = fmaxf(w, 0.0f) + log1pf(__expf(-fabsf(w)));

    int a = sx[e];
    int b = sy[e];
    float2 r = reinterpret_cast<const float2*>(rel)[e];

    const float* za = zin + (size_t)a * kZrow;
    const float* zb = zin + (size_t)b * kZrow;
    float4 a0 = reinterpret_cast<const float4*>(za)[0];
    float4 a1 = reinterpret_cast<const float4*>(za)[1];
    float2 a2 = reinterpret_cast<const float2*>(za + 8)[0];
    float4 b0 = reinterpret_cast<const float4*>(zb)[0];
    float4 b1v = reinterpret_cast<const float4*>(zb)[1];
    float2 b2v = reinterpret_cast<const float2*>(zb + 8)[0];

    float t[22];
    t[0]  =  a0.x;  t[1]  = -a0.y;  t[2]  =  a0.z;  t[3]  = -a0.w;
    t[4]  =  a1.x;  t[5]  = -a1.y;  t[6]  =  a1.z;  t[7]  = -a1.w;
    t[8]  =  a2.x;  t[9]  = -a2.y;
    t[10] =  b0.x;  t[11] = -b0.y;  t[12] =  b0.z;  t[13] = -b0.w;
    t[14] =  b1v.x; t[15] = -b1v.y; t[16] =  b1v.z; t[17] = -b1v.w;
    t[18] =  b2v.x; t[19] = -b2v.y;
    t[20] =  r.x;   t[21] = -r.y;

    float m = t[0];
    #pragma unroll
    for (int i = 1; i < 22; ++i) m = fmaxf(m, t[i]);
    float p[22]; float s = 0.0f;
    #pragma unroll
    for (int i = 0; i < 22; ++i) { p[i] = __expf(t[i] - m); s += p[i]; }
    float scale = sw / s;

    float* oa = zout + (size_t)a * kZrow;
    float* ob = zout + (size_t)b * kZrow;
    #pragma unroll
    for (int i = 0; i < 10; ++i)
        unsafeAtomicAdd(oa + i, ((i & 1) ? -scale : scale) * p[i]);
    #pragma unroll
    for (int i = 0; i < 10; ++i)
        unsafeAtomicAdd(ob + i, ((i & 1) ? -scale : scale) * p[10 + i]);
}

// ---------------------------------------------------------------------------
extern "C" void kernel_launch(void* const* d_in, const int* in_sizes, int n_in,
                              void* d_out, int out_size, void* d_ws, size_t ws_size,
                              hipStream_t stream)
{
    const float* feat = (const float*)d_in[0];
    const float* rel  = (const float*)d_in[1];
    const float* W1   = (const float*)d_in[2];
    const float* b1   = (const float*)d_in[3];
    const float* W2   = (const float*)d_in[4];
    const float* b2   = (const float*)d_in[5];
    const float* cw   = (const float*)d_in[6];
    const int*   sx   = (const int*)d_in[7];
    const int*   sy   = (const int*)d_in[8];
    float* out = (float*)d_out;

    // ws layout (bytes). kCBCap=66800 keeps tier1 within the PROVEN >=196993280.
    char* ws = (char*)d_ws;
    const size_t off_zA      = 0;                       // 4,800,000
    const size_t off_zB      = 4800000;                 // 4,800,000
    const size_t off_gcur    = 9600000;                 // 512
    const size_t off_rowptr  = 9600512;                 // 400,384
    const size_t off_rowcnt  = 10000896;                // 400,384
    const size_t off_seghist = 10401280;                // 98*8*1024*4 = 3,211,264
    const size_t off_bkey    = 13612544;                // 98*66800*4  = 26,185,600
    const size_t off_brel    = 39798144;                // 98*66800*8  = 52,371,200
    const size_t off_sdata   = 92169344;                // 98*66800*16 = 104,742,400
    const size_t need_t1     = 196911744;               // <= proven 196,993,280
    const size_t off_skey    = off_sdata;               // tier2: 26,185,600
    const size_t off_srel    = 118354944;               // tier2: 52,371,200
    const size_t need_t2     = 170726144;

    float*    zA      = (float*)(ws + off_zA);
    float*    zB      = (float*)(ws + off_zB);
    int*      gcur    = (int*)(ws + off_gcur);
    int*      rowptr  = (int*)(ws + off_rowptr);
    int*      rowcnt  = (int*)(ws + off_rowcnt);
    int*      seghist = (int*)(ws + off_seghist);
    unsigned* bkey    = (unsigned*)(ws + off_bkey);
    float2*   brel    = (float2*)(ws + off_brel);
    uint4*    sdata   = (uint4*)(ws + off_sdata);
    unsigned* skey    = (unsigned*)(ws + off_skey);
    float2*   srel    = (float2*)(ws + off_srel);

    dim3 blk(256);
    dim3 gN((kN + 255) / 256);
    dim3 gE((kE + 255) / 256);
    dim3 gB((kE + kChunkE - 1) / kChunkE);
    dim3 gG(kN / 16);                       // 6250
    dim3 gM((kN + 63) / 64);                // 1563 blocks, 4 waves each
    dim3 gS(kCB * kSeg);                    // 784 blocks

    mlp_kernel4<<<gM, blk, 0, stream>>>(feat, W1, b1, W2, b2, zA);

    if (ws_size >= need_t1) {
        hipMemsetAsync(gcur, 0, 512, stream);
        bucketize<<<gB, blk, 0, stream>>>(sx, sy, rel, gcur, bkey, brel);
        seg_hist   <<<gS, dim3(1024), 0, stream>>>(gcur, bkey, seghist);
        seg_base   <<<dim3(kCB), dim3(1024), 0, stream>>>(seghist, rowptr, rowcnt);
        seg_scatter<<<gS, dim3(1024), 0, stream>>>(gcur, bkey, brel, seghist, sdata);
        gather16<<<gG, blk, 0, stream>>>(zA, zB, sdata, rowptr, rowcnt, cw, 0);
        gather16<<<gG, blk, 0, stream>>>(zB, zA, sdata, rowptr, rowcnt, cw, 1);
        gather16_out<<<gG, blk, 0, stream>>>(zA, out, sdata, rowptr, rowcnt, cw, 2);
    } else if (ws_size >= need_t2) {
        hipMemsetAsync(gcur, 0, 512, stream);
        bucketize<<<gB, blk, 0, stream>>>(sx, sy, rel, gcur, bkey, brel);
        sort_bucket<<<dim3(kCB), dim3(1024), 0, stream>>>(gcur, bkey, brel,
                                                          skey, srel, rowptr, rowcnt);
        kenn_gather_csr<<<gG, blk, 0, stream>>>(zA, zB, skey, srel, rowptr, rowcnt, cw, 0);
        kenn_gather_csr<<<gG, blk, 0, stream>>>(zB, zA, skey, srel, rowptr, rowcnt, cw, 1);
        kenn_gather_csr<<<gG, blk, 0, stream>>>(zA, zB, skey, srel, rowptr, rowcnt, cw, 2);
        out_kernel<<<gN, blk, 0, stream>>>(zB, out);
    } else {
        size_t zbytes = (size_t)kN * kZrow * sizeof(float);
        hipMemcpyAsync(zB, zA, zbytes, hipMemcpyDeviceToDevice, stream);
        edge_kernel<<<gE, blk, 0, stream>>>(zA, zB, rel, sx, sy, cw, 0);
        hipMemcpyAsync(zA, zB, zbytes, hipMemcpyDeviceToDevice, stream);
        edge_kernel<<<gE, blk, 0, stream>>>(zB, zA, rel, sx, sy, cw, 1);
        hipMemcpyAsync(zB, zA, zbytes, hipMemcpyDeviceToDevice, stream);
        edge_kernel<<<gE, blk, 0, stream>>>(zA, zB, rel, sx, sy, cw, 2);
        out_kernel<<<gN, blk, 0, stream>>>(zB, out);
    }
}

// Round 11
// 559.077 us; speedup vs baseline: 2.8207x; 1.0009x over previous
//
#include <hip/hip_runtime.h>
#include <math.h>

constexpr int kN    = 100000;
constexpr int kE    = 3200000;
constexpr int kHid  = 1024;
constexpr int kZrow = 12;

// coarse buckets: 1024 nodes each
constexpr int kCBShift = 10;
constexpr int kCBNodes = 1 << kCBShift;                    // 1024
constexpr int kCB      = (kN + kCBNodes - 1) / kCBNodes;   // 98
constexpr int kCBCap   = 66800;                            // mean 65306, +5.8 sigma
constexpr int kSeg     = 8;                                // scatter segments/bucket
constexpr int kChunkE  = 1024;                             // edges per bucketize block
constexpr int kChunkEnt= kChunkE * 2;

// key layout: partner[16:0] | own_local[26:17] | side[27]

// ---------------------------------------------------------------------------
// Kernel 1: per-node MLP + derived columns. 4 waves split the 1024 hidden
// units of 64 nodes; LDS reduce (R9: 182 -> ~50 us, occupancy fix).
// ---------------------------------------------------------------------------
__global__ __launch_bounds__(256) void mlp_kernel4(
    const float* __restrict__ feat,
    const float* __restrict__ W1,
    const float* __restrict__ b1,
    const float* __restrict__ W2,
    const float* __restrict__ b2,
    float* __restrict__ z)
{
    __shared__ float red[4][8][64];          // [wave][out][node-lane], 8 KB

    int wave = (int)__builtin_amdgcn_readfirstlane(threadIdx.x >> 6);
    int lane = threadIdx.x & 63;
    int n    = blockIdx.x * 64 + lane;
    bool valid = n < kN;
    int nc   = valid ? n : (kN - 1);

    const float4* fr = reinterpret_cast<const float4*>(feat + (size_t)nc * 12);
    float4 f0 = fr[0], f1 = fr[1], f2 = fr[2];
    float f[12] = {f0.x, f0.y, f0.z, f0.w,
                   f1.x, f1.y, f1.z, f1.w,
                   f2.x, f2.y, f2.z, f2.w};

    float acc[8] = {0,0,0,0,0,0,0,0};
    int k0 = wave * (kHid / 4);
    int k1 = k0 + (kHid / 4);

    #pragma unroll 4
    for (int k = k0; k < k1; ++k) {
        float h = b1[k];
        #pragma unroll
        for (int d = 0; d < 12; ++d) h = fmaf(f[d], W1[d * kHid + k], h);
        h = fmaxf(h, 0.0f);
        #pragma unroll
        for (int o = 0; o < 8; ++o) acc[o] = fmaf(h, W2[k * 8 + o], acc[o]);
    }

    #pragma unroll
    for (int o = 0; o < 8; ++o) red[wave][o][lane] = acc[o];
    __syncthreads();

    if (wave == 0 && valid) {
        float a[8];
        #pragma unroll
        for (int o = 0; o < 8; ++o)
            a[o] = red[0][o][lane] + red[1][o][lane] +
                   red[2][o][lane] + red[3][o][lane] + b2[o];

        float ymin_diff = (f[2] - f[10]) * 10.0f;
        bool mask = (f[0] <= f[5]) && (f[1] >= f[4]) &&
                    (f[2] <= f[11]) && (f[3] >= f[10]);
        float inter = mask ? 5.0f : -5.0f;

        float* zr = z + (size_t)n * kZrow;
        reinterpret_cast<float4*>(zr)[0] = {a[0], a[1], a[2], a[3]};
        reinterpret_cast<float4*>(zr)[1] = {a[4], a[5], a[6], a[7]};
        reinterpret_cast<float4*>(zr)[2] = {ymin_diff, inter, 0.0f, 0.0f};
    }
}

// ---------------------------------------------------------------------------
// Kernel 2: bucketize, single-atomic-pass + search-free flush (R11 rework).
// Each entry: one LDS atomic (count=position), stage scatter with precomputed
// global dst, linear flush with rel gathered from the L1-resident 8KB window.
// ---------------------------------------------------------------------------
__global__ __launch_bounds__(256) void bucketize(
    const int* __restrict__ sx,
    const int* __restrict__ sy,
    const float* __restrict__ rel,
    int* __restrict__ gcur,
    unsigned* __restrict__ bkey,
    float2* __restrict__ brel)
{
    __shared__ int      cnt[128];
    __shared__ int      scn[128];
    __shared__ int      startArr[128];
    __shared__ int      gbase[128];
    __shared__ unsigned stage_k[kChunkEnt];   // 8 KB
    __shared__ int      stage_d[kChunkEnt];   // 8 KB  global dst (or -1)
    __shared__ int      stage_e[kChunkEnt];   // 8 KB  chunk-local edge idx

    int tid  = threadIdx.x;
    int e0   = blockIdx.x * kChunkE;
    int ecnt = min(kChunkE, kE - e0);

    if (tid < 128) cnt[tid] = 0;
    __syncthreads();

    // Phase A: single atomic pass; position doubles as count.
    int ea[4], eb[4], pa[4], pb[4];
    #pragma unroll
    for (int u = 0; u < 4; ++u) {
        int i = tid + u * 256;
        if (i < ecnt) {
            int a = sx[e0 + i];
            int b = sy[e0 + i];
            ea[u] = a; eb[u] = b;
            pa[u] = atomicAdd(&cnt[a >> kCBShift], 1);
            pb[u] = atomicAdd(&cnt[b >> kCBShift], 1);
        }
    }
    __syncthreads();

    // Scan cnt -> startArr (exclusive); reserve global ranges.
    if (tid < 128) scn[tid] = cnt[tid];
    __syncthreads();
    for (int off = 1; off < 128; off <<= 1) {
        int v = 0;
        if (tid < 128 && tid >= off) v = scn[tid - off];
        __syncthreads();
        if (tid < 128) scn[tid] += v;
        __syncthreads();
    }
    if (tid < 128) {
        startArr[tid] = scn[tid] - cnt[tid];
        int c = cnt[tid];
        gbase[tid] = (c > 0) ? atomicAdd(&gcur[tid], c) : 0;
    }
    __syncthreads();

    // Stage: scatter into bucket-sorted LDS order; precompute global dst.
    #pragma unroll
    for (int u = 0; u < 4; ++u) {
        int i = tid + u * 256;
        if (i < ecnt) {
            int a = ea[u], b = eb[u];
            int ba = a >> kCBShift, bb = b >> kCBShift;

            int sa = startArr[ba] + pa[u];
            int ia = gbase[ba] + pa[u];
            stage_k[sa] = (unsigned)b | ((unsigned)(a & (kCBNodes - 1)) << 17);
            stage_d[sa] = (ia < kCBCap) ? (ba * kCBCap + ia) : -1;
            stage_e[sa] = i;

            int sb = startArr[bb] + pb[u];
            int ib = gbase[bb] + pb[u];
            stage_k[sb] = (unsigned)a | ((unsigned)(b & (kCBNodes - 1)) << 17) | (1u << 27);
            stage_d[sb] = (ib < kCBCap) ? (bb * kCBCap + ib) : -1;
            stage_e[sb] = i;
        }
    }
    __syncthreads();

    // Flush: linear over staged slots, no search. rel window is 8KB contiguous.
    int total = 2 * ecnt;
    for (int j = tid; j < total; j += 256) {
        int dst = stage_d[j];
        unsigned k = stage_k[j];
        int e = stage_e[j];
        float2 r = reinterpret_cast<const float2*>(rel)[e0 + e];
        if (dst >= 0) {
            bkey[dst] = k;
            brel[dst] = r;
        }
    }
}

// ---------------------------------------------------------------------------
// Sort phase A: per-(bucket,segment) node histogram. 784 blocks.
// ---------------------------------------------------------------------------
__global__ __launch_bounds__(1024) void seg_hist(
    const int* __restrict__ gcur,
    const unsigned* __restrict__ bkey,
    int* __restrict__ seghist)
{
    __shared__ int hist[kCBNodes];

    int tid = threadIdx.x;
    int b   = blockIdx.x / kSeg;
    int s   = blockIdx.x % kSeg;
    int n   = min(gcur[b], kCBCap);
    int j0  = (int)((long long)n * s / kSeg);
    int j1  = (int)((long long)n * (s + 1) / kSeg);
    const unsigned* bk = bkey + (size_t)b * kCBCap;

    hist[tid] = 0;
    __syncthreads();

    for (int j = j0 + tid; j < j1; j += 1024)
        atomicAdd(&hist[(bk[j] >> 17) & 1023u], 1);
    __syncthreads();

    seghist[(size_t)blockIdx.x * kCBNodes + tid] = hist[tid];
}

// ---------------------------------------------------------------------------
// Sort phase B: per bucket, rowcnt/rowptr + per-segment base cursors. 98 blocks.
// ---------------------------------------------------------------------------
__global__ __launch_bounds__(1024) void seg_base(
    int* __restrict__ seghist,     // in: counts, out: base cursors (in-place)
    int* __restrict__ rowptr,
    int* __restrict__ rowcnt)
{
    __shared__ int scanb[kCBNodes];

    int tid = threadIdx.x;
    int b   = blockIdx.x;

    int c[kSeg];
    int tot = 0;
    #pragma unroll
    for (int s = 0; s < kSeg; ++s) {
        c[s] = seghist[((size_t)(b * kSeg + s)) * kCBNodes + tid];
        tot += c[s];
    }

    scanb[tid] = tot;
    __syncthreads();
    for (int off = 1; off < kCBNodes; off <<= 1) {
        int v = (tid >= off) ? scanb[tid - off] : 0;
        __syncthreads();
        scanb[tid] += v;
        __syncthreads();
    }
    int excl = scanb[tid] - tot;

    int node = (b << kCBShift) + tid;
    if (node < kN) {
        rowptr[node] = b * kCBCap + excl;
        rowcnt[node] = tot;
    }

    int base = excl;
    #pragma unroll
    for (int s = 0; s < kSeg; ++s) {
        seghist[((size_t)(b * kSeg + s)) * kCBNodes + tid] = base;
        base += c[s];
    }
}

// ---------------------------------------------------------------------------
// Sort phase C: segmented scatter with LDS cursors. 784 blocks -> all CUs.
// ---------------------------------------------------------------------------
__global__ __launch_bounds__(1024) void seg_scatter(
    const int* __restrict__ gcur,
    const unsigned* __restrict__ bkey,
    const float2* __restrict__ brel,
    const int* __restrict__ seghist,
    uint4* __restrict__ sdata)
{
    __shared__ int cur[kCBNodes];

    int tid = threadIdx.x;
    int b   = blockIdx.x / kSeg;
    int s   = blockIdx.x % kSeg;
    int n   = min(gcur[b], kCBCap);
    int j0  = (int)((long long)n * s / kSeg);
    int j1  = (int)((long long)n * (s + 1) / kSeg);
    const unsigned* bk = bkey + (size_t)b * kCBCap;
    const float2*   br = brel + (size_t)b * kCBCap;

    cur[tid] = seghist[(size_t)blockIdx.x * kCBNodes + tid];
    __syncthreads();

    for (int j = j0 + tid; j < j1; j += 1024) {
        unsigned k = bk[j];
        float2  r  = br[j];
        int ol = (int)((k >> 17) & 1023u);
        int pos = atomicAdd(&cur[ol], 1);
        sdata[(size_t)b * kCBCap + pos] =
            make_uint4(k, __float_as_uint(r.x), __float_as_uint(r.y), 0u);
    }
}

// ---------------------------------------------------------------------------
// Kernel 4 (tier1): gather layer from 16B entries, register accumulation.
// ---------------------------------------------------------------------------
__global__ __launch_bounds__(256) void gather16(
    const float* __restrict__ zin,
    float* __restrict__ zout,
    const uint4* __restrict__ sdata,
    const int* __restrict__ rowptr,
    const int* __restrict__ rowcnt,
    const float* __restrict__ cw,
    int layer)
{
    int node = blockIdx.x * 16 + (threadIdx.x >> 4);
    int lane = threadIdx.x & 15;
    if (node >= kN) return;

    float w  = cw[layer];
    float sw = fmaxf(w, 0.0f) + log1pf(__expf(-fabsf(w)));  // softplus

    const float* zs = zin + (size_t)node * kZrow;
    float4 s0 = reinterpret_cast<const float4*>(zs)[0];
    float4 s1 = reinterpret_cast<const float4*>(zs)[1];
    float4 s2 = reinterpret_cast<const float4*>(zs)[2];
    float self[10] = {s0.x, s0.y, s0.z, s0.w, s1.x, s1.y, s1.z, s1.w, s2.x, s2.y};

    float acc[10] = {0,0,0,0,0,0,0,0,0,0};
    int rp = rowptr[node];
    int rc = rowcnt[node];

    for (int i = lane; i < rc; i += 16) {
        uint4 ent = sdata[rp + i];
        unsigned k = ent.x;
        float rx = __uint_as_float(ent.y);
        float ry = __uint_as_float(ent.z);
        int p    = (int)(k & 0x1FFFFu);
        int side = (int)((k >> 27) & 1u);

        const float* zp = zin + (size_t)p * kZrow;
        float4 p0 = reinterpret_cast<const float4*>(zp)[0];
        float4 p1 = reinterpret_cast<const float4*>(zp)[1];
        float2 p2 = reinterpret_cast<const float2*>(zp + 8)[0];
        float part[10] = {p0.x, p0.y, p0.z, p0.w, p1.x, p1.y, p1.z, p1.w, p2.x, p2.y};

        float t[22];
        #pragma unroll
        for (int j = 0; j < 10; ++j) {
            float ga = side ? part[j] : self[j];
            float gb = side ? self[j] : part[j];
            t[j]      = (j & 1) ? -ga : ga;
            t[10 + j] = (j & 1) ? -gb : gb;
        }
        t[20] = rx;
        t[21] = -ry;

        float m = t[0];
        #pragma unroll
        for (int j = 1; j < 22; ++j) m = fmaxf(m, t[j]);

        float pe[22];
        float ssum = 0.0f;
        #pragma unroll
        for (int j = 0; j < 22; ++j) { pe[j] = __expf(t[j] - m); ssum += pe[j]; }

        float scale = sw / ssum;
        #pragma unroll
        for (int j = 0; j < 10; ++j) {
            float pv = side ? pe[10 + j] : pe[j];
            acc[j] += ((j & 1) ? -scale : scale) * pv;
        }
    }

    #pragma unroll
    for (int m16 = 8; m16 >= 1; m16 >>= 1) {
        #pragma unroll
        for (int j = 0; j < 10; ++j)
            acc[j] += __shfl_xor(acc[j], m16, 16);
    }

    if (lane == 0) {
        float* zo = zout + (size_t)node * kZrow;
        reinterpret_cast<float4*>(zo)[0] =
            {self[0] + acc[0], self[1] + acc[1], self[2] + acc[2], self[3] + acc[3]};
        reinterpret_cast<float4*>(zo)[1] =
            {self[4] + acc[4], self[5] + acc[5], self[6] + acc[6], self[7] + acc[7]};
        reinterpret_cast<float4*>(zo)[2] =
            {self[8] + acc[8], self[9] + acc[9], s2.z, s2.w};
    }
}

// ---------------------------------------------------------------------------
// Kernel 5 (tier1): final gather layer fused with output heads.
// ---------------------------------------------------------------------------
__global__ __launch_bounds__(256) void gather16_out(
    const float* __restrict__ zin,
    float* __restrict__ out,
    const uint4* __restrict__ sdata,
    const int* __restrict__ rowptr,
    const int* __restrict__ rowcnt,
    const float* __restrict__ cw,
    int layer)
{
    int node = blockIdx.x * 16 + (threadIdx.x >> 4);
    int lane = threadIdx.x & 15;
    if (node >= kN) return;

    float w  = cw[layer];
    float sw = fmaxf(w, 0.0f) + log1pf(__expf(-fabsf(w)));

    const float* zs = zin + (size_t)node * kZrow;
    float4 s0 = reinterpret_cast<const float4*>(zs)[0];
    float4 s1 = reinterpret_cast<const float4*>(zs)[1];
    float4 s2 = reinterpret_cast<const float4*>(zs)[2];
    float self[10] = {s0.x, s0.y, s0.z, s0.w, s1.x, s1.y, s1.z, s1.w, s2.x, s2.y};

    float acc[8] = {0,0,0,0,0,0,0,0};
    int rp = rowptr[node];
    int rc = rowcnt[node];

    for (int i = lane; i < rc; i += 16) {
        uint4 ent = sdata[rp + i];
        unsigned k = ent.x;
        float rx = __uint_as_float(ent.y);
        float ry = __uint_as_float(ent.z);
        int p    = (int)(k & 0x1FFFFu);
        int side = (int)((k >> 27) & 1u);

        const float* zp = zin + (size_t)p * kZrow;
        float4 p0 = reinterpret_cast<const float4*>(zp)[0];
        float4 p1 = reinterpret_cast<const float4*>(zp)[1];
        float2 p2 = reinterpret_cast<const float2*>(zp + 8)[0];
        float part[10] = {p0.x, p0.y, p0.z, p0.w, p1.x, p1.y, p1.z, p1.w, p2.x, p2.y};

        float t[22];
        #pragma unroll
        for (int j = 0; j < 10; ++j) {
            float ga = side ? part[j] : self[j];
            float gb = side ? self[j] : part[j];
            t[j]      = (j & 1) ? -ga : ga;
            t[10 + j] = (j & 1) ? -gb : gb;
        }
        t[20] = rx;
        t[21] = -ry;

        float m = t[0];
        #pragma unroll
        for (int j = 1; j < 22; ++j) m = fmaxf(m, t[j]);

        float pe[22];
        float ssum = 0.0f;
        #pragma unroll
        for (int j = 0; j < 22; ++j) { pe[j] = __expf(t[j] - m); ssum += pe[j]; }

        float scale = sw / ssum;
        #pragma unroll
        for (int j = 0; j < 8; ++j) {
            float pv = side ? pe[10 + j] : pe[j];
            acc[j] += ((j & 1) ? -scale : scale) * pv;
        }
    }

    #pragma unroll
    for (int m16 = 8; m16 >= 1; m16 >>= 1) {
        #pragma unroll
        for (int j = 0; j < 8; ++j)
            acc[j] += __shfl_xor(acc[j], m16, 16);
    }

    if (lane == 0) {
        float4 za = {self[0] + acc[0], self[1] + acc[1], self[2] + acc[2], self[3] + acc[3]};
        float4 zb = {self[4] + acc[4], self[5] + acc[5], self[6] + acc[6], self[7] + acc[7]};

        float ma = fmaxf(fmaxf(za.x, za.y), fmaxf(za.z, za.w));
        float ea0 = __expf(za.x - ma), ea1 = __expf(za.y - ma);
        float ea2 = __expf(za.z - ma), ea3 = __expf(za.w - ma);
        float ia = 1.0f / (ea0 + ea1 + ea2 + ea3);
        float4 sma = {ea0 * ia, ea1 * ia, ea2 * ia, ea3 * ia};

        float mb = fmaxf(fmaxf(zb.x, zb.y), fmaxf(zb.z, zb.w));
        float eb0 = __expf(zb.x - mb), eb1 = __expf(zb.y - mb);
        float eb2 = __expf(zb.z - mb), eb3 = __expf(zb.w - mb);
        float ib = 1.0f / (eb0 + eb1 + eb2 + eb3);
        float4 smb = {eb0 * ib, eb1 * ib, eb2 * ib, eb3 * ib};

        reinterpret_cast<float4*>(out)[node]           = za;
        reinterpret_cast<float4*>(out + 4 * kN)[node]  = sma;
        reinterpret_cast<float4*>(out + 8 * kN)[node]  = zb;
        reinterpret_cast<float4*>(out + 12 * kN)[node] = smb;
    }
}

// ---------------------------------------------------------------------------
// Tier2 (R6-proven): single-block-per-bucket sort + gather + out.
// ---------------------------------------------------------------------------
__global__ __launch_bounds__(1024) void sort_bucket(
    const int* __restrict__ gcur,
    const unsigned* __restrict__ bkey,
    const float2* __restrict__ brel,
    unsigned* __restrict__ skey,
    float2* __restrict__ srel,
    int* __restrict__ rowptr,
    int* __restrict__ rowcnt)
{
    __shared__ int cnt1024[kCBNodes];
    __shared__ int scanb[kCBNodes];
    __shared__ int cur[kCBNodes];

    int tid = threadIdx.x;
    int b   = blockIdx.x;
    int n   = min(gcur[b], kCBCap);
    const unsigned* bk = bkey + (size_t)b * kCBCap;
    const float2*   br = brel + (size_t)b * kCBCap;

    cnt1024[tid] = 0;
    __syncthreads();
    for (int j = tid; j < n; j += 1024)
        atomicAdd(&cnt1024[(bk[j] >> 17) & 1023u], 1);
    __syncthreads();

    scanb[tid] = cnt1024[tid];
    __syncthreads();
    for (int off = 1; off < kCBNodes; off <<= 1) {
        int v = (tid >= off) ? scanb[tid - off] : 0;
        __syncthreads();
        scanb[tid] += v;
        __syncthreads();
    }
    int excl = scanb[tid] - cnt1024[tid];
    cur[tid] = excl;

    int node = (b << kCBShift) + tid;
    if (node < kN) {
        rowptr[node] = b * kCBCap + excl;
        rowcnt[node] = cnt1024[tid];
    }
    __syncthreads();

    for (int j = tid; j < n; j += 1024) {
        unsigned k = bk[j];
        float2  r  = br[j];
        int ol = (int)((k >> 17) & 1023u);
        int pos = atomicAdd(&cur[ol], 1);
        size_t dst = (size_t)b * kCBCap + pos;
        skey[dst] = k;
        srel[dst] = r;
    }
}

__global__ __launch_bounds__(256) void kenn_gather_csr(
    const float* __restrict__ zin,
    float* __restrict__ zout,
    const unsigned* __restrict__ skey,
    const float2* __restrict__ srel,
    const int* __restrict__ rowptr,
    const int* __restrict__ rowcnt,
    const float* __restrict__ cw,
    int layer)
{
    int node = blockIdx.x * 16 + (threadIdx.x >> 4);
    int lane = threadIdx.x & 15;
    if (node >= kN) return;

    float w  = cw[layer];
    float sw = fmaxf(w, 0.0f) + log1pf(__expf(-fabsf(w)));

    const float* zs = zin + (size_t)node * kZrow;
    float4 s0 = reinterpret_cast<const float4*>(zs)[0];
    float4 s1 = reinterpret_cast<const float4*>(zs)[1];
    float4 s2 = reinterpret_cast<const float4*>(zs)[2];
    float self[10] = {s0.x, s0.y, s0.z, s0.w, s1.x, s1.y, s1.z, s1.w, s2.x, s2.y};

    float acc[10] = {0,0,0,0,0,0,0,0,0,0};
    int rp = rowptr[node];
    int rc = rowcnt[node];

    for (int i = lane; i < rc; i += 16) {
        unsigned k = skey[rp + i];
        float2  r  = srel[rp + i];
        int p    = (int)(k & 0x1FFFFu);
        int side = (int)((k >> 27) & 1u);

        const float* zp = zin + (size_t)p * kZrow;
        float4 p0 = reinterpret_cast<const float4*>(zp)[0];
        float4 p1 = reinterpret_cast<const float4*>(zp)[1];
        float2 p2 = reinterpret_cast<const float2*>(zp + 8)[0];
        float part[10] = {p0.x, p0.y, p0.z, p0.w, p1.x, p1.y, p1.z, p1.w, p2.x, p2.y};

        float t[22];
        #pragma unroll
        for (int j = 0; j < 10; ++j) {
            float ga = side ? part[j] : self[j];
            float gb = side ? self[j] : part[j];
            t[j]      = (j & 1) ? -ga : ga;
            t[10 + j] = (j & 1) ? -gb : gb;
        }
        t[20] = r.x;
        t[21] = -r.y;

        float m = t[0];
        #pragma unroll
        for (int j = 1; j < 22; ++j) m = fmaxf(m, t[j]);

        float pe[22];
        float ssum = 0.0f;
        #pragma unroll
        for (int j = 0; j < 22; ++j) { pe[j] = __expf(t[j] - m); ssum += pe[j]; }

        float scale = sw / ssum;
        #pragma unroll
        for (int j = 0; j < 10; ++j) {
            float pv = side ? pe[10 + j] : pe[j];
            acc[j] += ((j & 1) ? -scale : scale) * pv;
        }
    }

    #pragma unroll
    for (int m16 = 8; m16 >= 1; m16 >>= 1) {
        #pragma unroll
        for (int j = 0; j < 10; ++j)
            acc[j] += __shfl_xor(acc[j], m16, 16);
    }

    if (lane == 0) {
        float* zo = zout + (size_t)node * kZrow;
        reinterpret_cast<float4*>(zo)[0] =
            {self[0] + acc[0], self[1] + acc[1], self[2] + acc[2], self[3] + acc[3]};
        reinterpret_cast<float4*>(zo)[1] =
            {self[4] + acc[4], self[5] + acc[5], self[6] + acc[6], self[7] + acc[7]};
        reinterpret_cast<float4*>(zo)[2] =
            {self[8] + acc[8], self[9] + acc[9], s2.z, s2.w};
    }
}

__global__ __launch_bounds__(256) void out_kernel(
    const float* __restrict__ z,
    float* __restrict__ out)
{
    int n = blockIdx.x * blockDim.x + threadIdx.x;
    if (n >= kN) return;

    const float* zr = z + (size_t)n * kZrow;
    float4 za = reinterpret_cast<const float4*>(zr)[0];
    float4 zb = reinterpret_cast<const float4*>(zr)[1];

    float ma = fmaxf(fmaxf(za.x, za.y), fmaxf(za.z, za.w));
    float ea0 = __expf(za.x - ma), ea1 = __expf(za.y - ma);
    float ea2 = __expf(za.z - ma), ea3 = __expf(za.w - ma);
    float ia = 1.0f / (ea0 + ea1 + ea2 + ea3);
    float4 sma = {ea0 * ia, ea1 * ia, ea2 * ia, ea3 * ia};

    float mb = fmaxf(fmaxf(zb.x, zb.y), fmaxf(zb.z, zb.w));
    float eb0 = __expf(zb.x - mb), eb1 = __expf(zb.y - mb);
    float eb2 = __expf(zb.z - mb), eb3 = __expf(zb.w - mb);
    float ib = 1.0f / (eb0 + eb1 + eb2 + eb3);
    float4 smb = {eb0 * ib, eb1 * ib, eb2 * ib, eb3 * ib};

    reinterpret_cast<float4*>(out)[n]           = za;
    reinterpret_cast<float4*>(out + 4 * kN)[n]  = sma;
    reinterpret_cast<float4*>(out + 8 * kN)[n]  = zb;
    reinterpret_cast<float4*>(out + 12 * kN)[n] = smb;
}

// ---------------------------------------------------------------------------
// Tier3 (R1-proven): atomic scatter, minimal ws.
// ---------------------------------------------------------------------------
__global__ __launch_bounds__(256) void edge_kernel(
    const float* __restrict__ zin,
    float* __restrict__ zout,
    const float* __restrict__ rel,
    const int* __restrict__ sx,
    const int* __restrict__ sy,
    const float* __restrict__ cw,
    int layer)
{
    int e = blockIdx.x * blockDim.x + threadIdx.x;
    if (e >= kE) return;

    float w  = cw[layer];
    float sw = fmaxf(w, 0.0f) + log1pf(__expf(-fabsf(w)));

    int a = sx[e];
    int b = sy[e];
    float2 r = reinterpret_cast<const float2*>(rel)[e];

    const float* za = zin + (size_t)a * kZrow;
    const float* zb = zin + (size_t)b * kZrow;
    float4 a0 = reinterpret_cast<const float4*>(za)[0];
    float4 a1 = reinterpret_cast<const float4*>(za)[1];
    float2 a2 = reinterpret_cast<const float2*>(za + 8)[0];
    float4 b0 = reinterpret_cast<const float4*>(zb)[0];
    float4 b1v = reinterpret_cast<const float4*>(zb)[1];
    float2 b2v = reinterpret_cast<const float2*>(zb + 8)[0];

    float t[22];
    t[0]  =  a0.x;  t[1]  = -a0.y;  t[2]  =  a0.z;  t[3]  = -a0.w;
    t[4]  =  a1.x;  t[5]  = -a1.y;  t[6]  =  a1.z;  t[7]  = -a1.w;
    t[8]  =  a2.x;  t[9]  = -a2.y;
    t[10] =  b0.x;  t[11] = -b0.y;  t[12] =  b0.z;  t[13] = -b0.w;
    t[14] =  b1v.x; t[15] = -b1v.y; t[16] =  b1v.z; t[17] = -b1v.w;
    t[18] =  b2v.x; t[19] = -b2v.y;
    t[20] =  r.x;   t[21] = -r.y;

    float m = t[0];
    #pragma unroll
    for (int i = 1; i < 22; ++i) m = fmaxf(m, t[i]);
    float p[22]; float s = 0.0f;
    #pragma unroll
    for (int i = 0; i < 22; ++i) { p[i] = __expf(t[i] - m); s += p[i]; }
    float scale = sw / s;

    float* oa = zout + (size_t)a * kZrow;
    float* ob = zout + (size_t)b * kZrow;
    #pragma unroll
    for (int i = 0; i < 10; ++i)
        unsafeAtomicAdd(oa + i, ((i & 1) ? -scale : scale) * p[i]);
    #pragma unroll
    for (int i = 0; i < 10; ++i)
        unsafeAtomicAdd(ob + i, ((i & 1) ? -scale : scale) * p[10 + i]);
}

// ---------------------------------------------------------------------------
extern "C" void kernel_launch(void* const* d_in, const int* in_sizes, int n_in,
                              void* d_out, int out_size, void* d_ws, size_t ws_size,
                              hipStream_t stream)
{
    const float* feat = (const float*)d_in[0];
    const float* rel  = (const float*)d_in[1];
    const float* W1   = (const float*)d_in[2];
    const float* b1   = (const float*)d_in[3];
    const float* W2   = (const float*)d_in[4];
    const float* b2   = (const float*)d_in[5];
    const float* cw   = (const float*)d_in[6];
    const int*   sx   = (const int*)d_in[7];
    const int*   sy   = (const int*)d_in[8];
    float* out = (float*)d_out;

    // ws layout (bytes). kCBCap=66800 keeps tier1 within the PROVEN >=196993280.
    char* ws = (char*)d_ws;
    const size_t off_zA      = 0;                       // 4,800,000
    const size_t off_zB      = 4800000;                 // 4,800,000
    const size_t off_gcur    = 9600000;                 // 512
    const size_t off_rowptr  = 9600512;                 // 400,384
    const size_t off_rowcnt  = 10000896;                // 400,384
    const size_t off_seghist = 10401280;                // 98*8*1024*4 = 3,211,264
    const size_t off_bkey    = 13612544;                // 98*66800*4  = 26,185,600
    const size_t off_brel    = 39798144;                // 98*66800*8  = 52,371,200
    const size_t off_sdata   = 92169344;                // 98*66800*16 = 104,742,400
    const size_t need_t1     = 196911744;               // <= proven 196,993,280
    const size_t off_skey    = off_sdata;               // tier2: 26,185,600
    const size_t off_srel    = 118354944;               // tier2: 52,371,200
    const size_t need_t2     = 170726144;

    float*    zA      = (float*)(ws + off_zA);
    float*    zB      = (float*)(ws + off_zB);
    int*      gcur    = (int*)(ws + off_gcur);
    int*      rowptr  = (int*)(ws + off_rowptr);
    int*      rowcnt  = (int*)(ws + off_rowcnt);
    int*      seghist = (int*)(ws + off_seghist);
    unsigned* bkey    = (unsigned*)(ws + off_bkey);
    float2*   brel    = (float2*)(ws + off_brel);
    uint4*    sdata   = (uint4*)(ws + off_sdata);
    unsigned* skey    = (unsigned*)(ws + off_skey);
    float2*   srel    = (float2*)(ws + off_srel);

    dim3 blk(256);
    dim3 gN((kN + 255) / 256);
    dim3 gE((kE + 255) / 256);
    dim3 gB((kE + kChunkE - 1) / kChunkE);
    dim3 gG(kN / 16);                       // 6250
    dim3 gM((kN + 63) / 64);                // 1563 blocks, 4 waves each
    dim3 gS(kCB * kSeg);                    // 784 blocks

    mlp_kernel4<<<gM, blk, 0, stream>>>(feat, W1, b1, W2, b2, zA);

    if (ws_size >= need_t1) {
        hipMemsetAsync(gcur, 0, 512, stream);
        bucketize<<<gB, blk, 0, stream>>>(sx, sy, rel, gcur, bkey, brel);
        seg_hist   <<<gS, dim3(1024), 0, stream>>>(gcur, bkey, seghist);
        seg_base   <<<dim3(kCB), dim3(1024), 0, stream>>>(seghist, rowptr, rowcnt);
        seg_scatter<<<gS, dim3(1024), 0, stream>>>(gcur, bkey, brel, seghist, sdata);
        gather16<<<gG, blk, 0, stream>>>(zA, zB, sdata, rowptr, rowcnt, cw, 0);
        gather16<<<gG, blk, 0, stream>>>(zB, zA, sdata, rowptr, rowcnt, cw, 1);
        gather16_out<<<gG, blk, 0, stream>>>(zA, out, sdata, rowptr, rowcnt, cw, 2);
    } else if (ws_size >= need_t2) {
        hipMemsetAsync(gcur, 0, 512, stream);
        bucketize<<<gB, blk, 0, stream>>>(sx, sy, rel, gcur, bkey, brel);
        sort_bucket<<<dim3(kCB), dim3(1024), 0, stream>>>(gcur, bkey, brel,
                                                          skey, srel, rowptr, rowcnt);
        kenn_gather_csr<<<gG, blk, 0, stream>>>(zA, zB, skey, srel, rowptr, rowcnt, cw, 0);
        kenn_gather_csr<<<gG, blk, 0, stream>>>(zB, zA, skey, srel, rowptr, rowcnt, cw, 1);
        kenn_gather_csr<<<gG, blk, 0, stream>>>(zA, zB, skey, srel, rowptr, rowcnt, cw, 2);
        out_kernel<<<gN, blk, 0, stream>>>(zB, out);
    } else {
        size_t zbytes = (size_t)kN * kZrow * sizeof(float);
        hipMemcpyAsync(zB, zA, zbytes, hipMemcpyDeviceToDevice, stream);
        edge_kernel<<<gE, blk, 0, stream>>>(zA, zB, rel, sx, sy, cw, 0);
        hipMemcpyAsync(zA, zB, zbytes, hipMemcpyDeviceToDevice, stream);
        edge_kernel<<<gE, blk, 0, stream>>>(zB, zA, rel, sx, sy, cw, 1);
        hipMemcpyAsync(zB, zA, zbytes, hipMemcpyDeviceToDevice, stream);
        edge_kernel<<<gE, blk, 0, stream>>>(zA, zB, rel, sx, sy, cw, 2);
        out_kernel<<<gN, blk, 0, stream>>>(zB, out);
    }
}